// Round 6
// baseline (224.200 us; speedup 1.0000x reference)
//
#include <hip/hip_runtime.h>
#include <hip/hip_bf16.h>

#define B_    4
#define C_    64
#define MVOX  32768      // 32*32*32
#define NATOM 64
#define EMB_  128

typedef __attribute__((ext_vector_type(8))) __bf16 bf16x8;
typedef __attribute__((ext_vector_type(4))) float f32x4;
typedef __attribute__((ext_vector_type(8))) unsigned short ushort8;

typedef __attribute__((address_space(1))) const unsigned int gas_u32;
typedef __attribute__((address_space(3))) unsigned int las_u32;

// ---------------------------------------------------------------------------
// Kernel 0: weight prep.
//  Wt3 (conv): [tap][w][kh][lane][j] bf16, co = w*16+(lane&15),
//              ci = kh*32+(lane>>4)*8+j  -> per-wave coalesced A-frag loads.
//  Wqb: [nf][kk][lane][j] bf16 = Wq[nf*16+(lane&15)][kk*32+(lane>>4)*8+j] / sqrt(8)
//  Wob: same layout from Wo, unscaled.
// ---------------------------------------------------------------------------
__global__ __launch_bounds__(256) void wprep_kernel(
    const float* __restrict__ Wc, const float* __restrict__ Wq,
    const float* __restrict__ Wo,
    __hip_bfloat16* __restrict__ Wt3, __hip_bfloat16* __restrict__ Wqb,
    __hip_bfloat16* __restrict__ Wob) {
  const int i = blockIdx.x * 256 + threadIdx.x;
  if (i < 110592) {                                   // conv weights
    const int tap = i >> 12;
    const int w3  = (i >> 10) & 3;
    const int kh  = (i >> 9) & 1;
    const int l   = (i >> 3) & 63;
    const int j   = i & 7;
    const int co  = w3 * 16 + (l & 15);
    const int ci  = kh * 32 + ((l >> 4) << 3) + j;
    Wt3[i] = __float2bfloat16(Wc[(co * C_ + ci) * 27 + tap]);
  } else if (i < 114688) {                            // Wq (scaled)
    const int i2 = i - 110592;
    const int nf = (i2 >> 10) & 3;
    const int kk = (i2 >> 9) & 1;
    const int l  = (i2 >> 3) & 63;
    const int j  = i2 & 7;
    const int co = nf * 16 + (l & 15);
    const int ci = kk * 32 + ((l >> 4) << 3) + j;
    Wqb[i2] = __float2bfloat16(Wq[co * C_ + ci] * 0.3535533905932738f);
  } else if (i < 118784) {                            // Wo
    const int i3 = i - 114688;
    const int nf = (i3 >> 10) & 3;
    const int kk = (i3 >> 9) & 1;
    const int l  = (i3 >> 3) & 63;
    const int j  = i3 & 7;
    const int co = nf * 16 + (l & 15);
    const int ci = kk * 32 + ((l >> 4) << 3) + j;
    Wob[i3] = __float2bfloat16(Wo[co * C_ + ci]);
  }
}

// ---------------------------------------------------------------------------
// Kernel 1: K/V projections (tiny)
// ---------------------------------------------------------------------------
__global__ __launch_bounds__(256) void kv_kernel(
    const float* __restrict__ mol,
    const float* __restrict__ Wk, const float* __restrict__ bk,
    const float* __restrict__ Wv, const float* __restrict__ bv,
    float* __restrict__ kout, float* __restrict__ vout) {
  __shared__ float smol[NATOM * EMB_];
  __shared__ float sw[C_ * EMB_];
  const int b = blockIdx.x;
  const bool is_v = (blockIdx.y == 1);
  const float* W    = is_v ? Wv : Wk;
  const float* bias = is_v ? bv : bk;
  float* out        = is_v ? vout : kout;

  for (int i = threadIdx.x; i < NATOM * EMB_; i += 256) {
    smol[i] = mol[b * NATOM * EMB_ + i];
    sw[i]   = W[i];
  }
  __syncthreads();
  for (int idx = threadIdx.x; idx < NATOM * C_; idx += 256) {
    const int a = idx >> 6, c = idx & 63;
    float acc = bias[c];
    #pragma unroll 8
    for (int e = 0; e < EMB_; ++e) acc += smol[a * EMB_ + e] * sw[c * EMB_ + e];
    out[b * NATOM * C_ + idx] = acc;
  }
}

// ---------------------------------------------------------------------------
// Kernel 2: fused Q-proj(MFMA) + ragged attention(VALU) + O-proj(MFMA) + ReLU.
// 512 threads = 8 waves. Projection wave role: vq = w&3 (16-vox block),
// cq = w>>2 (32-co half). Attention thread role: (vox = tid&63, head = w).
// LDS: sk, sv, xq (x -> Q -> bf16 out exchange), os. 64 KB total.
// ---------------------------------------------------------------------------
__global__ __launch_bounds__(512, 4) void attn_kernel(
    const float* __restrict__ x,
    const float* __restrict__ kbuf, const float* __restrict__ vbuf,
    const int* __restrict__ batch_nodes,
    const __hip_bfloat16* __restrict__ Wqb, const float* __restrict__ bq,
    const __hip_bfloat16* __restrict__ Wob, const float* __restrict__ bo,
    __hip_bfloat16* __restrict__ omid) {
  __shared__ float sk[NATOM * C_];   // 16 KB
  __shared__ float sv[NATOM * C_];   // 16 KB
  __shared__ float xq[64 * C_];      // 16 KB: x[c][vox] -> Q[vox][c] -> osb
  __shared__ float os[64 * C_];      // 16 KB: attn-out [vox][c] swizzled

  const int b    = blockIdx.y;
  const int m0   = blockIdx.x * 64;
  const int tid  = threadIdx.x;
  const int vox  = tid & 63;
  const int lane = tid & 63;
  const int w    = __builtin_amdgcn_readfirstlane(tid >> 6);   // 0..7
  const int quad = lane >> 4;
  const int l15  = lane & 15;
  const int vq   = w & 3;            // vox block for projections
  const int cq   = w >> 2;           // co half for projections

  // ---- stage x tile [c][vox] (16 KB) via global_load_lds ----
  #pragma unroll
  for (int j = 0; j < 2; ++j) {
    const int cidx = w * 2 + j;                  // 0..15
    const int c  = cidx * 4 + (lane >> 4);
    const int v4 = (lane & 15) * 4;
    const float* gsrc = x + (size_t)(b * C_ + c) * MVOX + m0 + v4;
    __builtin_amdgcn_global_load_lds((gas_u32*)gsrc,
                                     (las_u32*)&xq[cidx * 256], 16, 0, 0);
  }
  for (int i = tid; i < NATOM * C_; i += 512) {
    sk[i] = kbuf[b * NATOM * C_ + i];
    sv[i] = vbuf[b * NATOM * C_ + i];
  }
  __syncthreads();

  // ---- Q projection via MFMA: D[vox][co], wave handles 16 vox x 32 co ----
  f32x4 qacc[2];
  {
    bf16x8 af[2];
    #pragma unroll
    for (int kk = 0; kk < 2; ++kk) {
      ushort8 au;
      #pragma unroll
      for (int j = 0; j < 8; ++j) {
        const int ci = kk * 32 + quad * 8 + j;
        __hip_bfloat16 hb = __float2bfloat16(xq[ci * 64 + vq * 16 + l15]);
        au[j] = *(unsigned short*)&hb;
      }
      af[kk] = __builtin_bit_cast(bf16x8, au);
    }
    #pragma unroll
    for (int nf2 = 0; nf2 < 2; ++nf2) {
      const int nf = cq * 2 + nf2;
      const float bqv = bq[nf * 16 + l15] * 0.3535533905932738f;
      qacc[nf2] = {bqv, bqv, bqv, bqv};
      #pragma unroll
      for (int kk = 0; kk < 2; ++kk) {
        const bf16x8 bf = *(const bf16x8*)(Wqb + (((nf * 2 + kk) << 6) + lane) * 8);
        qacc[nf2] = __builtin_amdgcn_mfma_f32_16x16x32_bf16(af[kk], bf, qacc[nf2], 0, 0, 0);
      }
    }
  }
  __syncthreads();   // all xq (x-phase) reads done

  // write Q to xq[vox][c] with 16B-chunk swizzle (c4 ^ (vox&15))
  #pragma unroll
  for (int nf2 = 0; nf2 < 2; ++nf2) {
    const int co = (cq * 2 + nf2) * 16 + l15;
    const int c4 = co >> 2, ce = co & 3;
    #pragma unroll
    for (int r = 0; r < 4; ++r) {
      const int vr = vq * 16 + quad * 4 + r;
      xq[vr * 64 + ((c4 ^ (vr & 15)) << 2) + ce] = qacc[nf2][r];
    }
  }
  __syncthreads();

  // ---- ragged attention (VALU), thread = (vox, head w) ----
  const int h = w;
  float qa[8];
  {
    const f32x4 q0 = *(const f32x4*)&xq[vox * 64 + (((h * 2)     ^ (vox & 15)) << 2)];
    const f32x4 q1 = *(const f32x4*)&xq[vox * 64 + (((h * 2 + 1) ^ (vox & 15)) << 2)];
    qa[0]=q0.x; qa[1]=q0.y; qa[2]=q0.z; qa[3]=q0.w;
    qa[4]=q1.x; qa[5]=q1.y; qa[6]=q1.z; qa[7]=q1.w;
  }
  const int nv = batch_nodes[b];
  float mrun = -1e30f, lsum = 0.f;
  float acc[8];
  #pragma unroll
  for (int d = 0; d < 8; ++d) acc[d] = 0.f;

  #pragma unroll
  for (int ch = 0; ch < 2; ++ch) {
    float l[32];
    float cmax = -1e30f;
    #pragma unroll
    for (int a = 0; a < 32; ++a) {
      const int atom = ch * 32 + a;
      const f32x4 k0 = *(const f32x4*)&sk[atom * C_ + h * 8];
      const f32x4 k1 = *(const f32x4*)&sk[atom * C_ + h * 8 + 4];
      float lg = qa[0]*k0.x + qa[1]*k0.y + qa[2]*k0.z + qa[3]*k0.w
               + qa[4]*k1.x + qa[5]*k1.y + qa[6]*k1.z + qa[7]*k1.w;
      lg = (atom < nv) ? lg : -1e30f;
      l[a] = lg;
      cmax = fmaxf(cmax, lg);
    }
    const float mnew = fmaxf(mrun, cmax);
    const float corr = __expf(mrun - mnew);
    lsum *= corr;
    #pragma unroll
    for (int d = 0; d < 8; ++d) acc[d] *= corr;
    #pragma unroll
    for (int a = 0; a < 32; ++a) {
      const int atom = ch * 32 + a;
      const float p = __expf(l[a] - mnew);
      lsum += p;
      const f32x4 v0 = *(const f32x4*)&sv[atom * C_ + h * 8];
      const f32x4 v1 = *(const f32x4*)&sv[atom * C_ + h * 8 + 4];
      acc[0] += p * v0.x;  acc[1] += p * v0.y;
      acc[2] += p * v0.z;  acc[3] += p * v0.w;
      acc[4] += p * v1.x;  acc[5] += p * v1.y;
      acc[6] += p * v1.z;  acc[7] += p * v1.w;
    }
    mrun = mnew;
  }
  const float inv = 1.f / lsum;

  // write attn out to os[vox][c] swizzled
  #pragma unroll
  for (int i = 0; i < 2; ++i) {
    const int c4 = h * 2 + i;
    f32x4 val;
    val.x = acc[i * 4 + 0] * inv; val.y = acc[i * 4 + 1] * inv;
    val.z = acc[i * 4 + 2] * inv; val.w = acc[i * 4 + 3] * inv;
    *(f32x4*)&os[vox * 64 + ((c4 ^ (vox & 15)) << 2)] = val;
  }
  __syncthreads();

  // ---- O projection via MFMA + ReLU -> bf16 exchange in xq ----
  {
    bf16x8 af[2];
    #pragma unroll
    for (int kk = 0; kk < 2; ++kk) {
      ushort8 au;
      #pragma unroll
      for (int j = 0; j < 8; ++j) {
        const int ci = kk * 32 + quad * 8 + j;
        const int c4 = ci >> 2;
        const float f = os[(vq * 16 + l15) * 64 + ((c4 ^ l15) << 2) + (ci & 3)];
        __hip_bfloat16 hb = __float2bfloat16(f);
        au[j] = *(unsigned short*)&hb;
      }
      af[kk] = __builtin_bit_cast(bf16x8, au);
    }
    f32x4 oacc[2];
    #pragma unroll
    for (int nf2 = 0; nf2 < 2; ++nf2) {
      const int nf = cq * 2 + nf2;
      const float bov = bo[nf * 16 + l15];
      oacc[nf2] = {bov, bov, bov, bov};
      #pragma unroll
      for (int kk = 0; kk < 2; ++kk) {
        const bf16x8 bf = *(const bf16x8*)(Wob + (((nf * 2 + kk) << 6) + lane) * 8);
        oacc[nf2] = __builtin_amdgcn_mfma_f32_16x16x32_bf16(af[kk], bf, oacc[nf2], 0, 0, 0);
      }
    }
    // relu + pack bf16 into xq alias at chunk' = chunk ^ (vox&7)
    unsigned short* osb = (unsigned short*)xq;
    #pragma unroll
    for (int nf2 = 0; nf2 < 2; ++nf2) {
      const int co = (cq * 2 + nf2) * 16 + l15;
      #pragma unroll
      for (int r = 0; r < 4; ++r) {
        const int vr = vq * 16 + quad * 4 + r;
        __hip_bfloat16 hb = __float2bfloat16(fmaxf(oacc[nf2][r], 0.f));
        osb[vr * 64 + (((co >> 3) ^ (vr & 7)) << 3) + (co & 7)] = *(unsigned short*)&hb;
      }
    }
  }
  __syncthreads();

  // ---- coalesced store: xq alias already holds conv's swizzled layout ----
  *(ushort8*)(omid + (size_t)(b * MVOX + m0) * C_ + tid * 8) =
      *(const ushort8*)&((unsigned short*)xq)[tid * 8];
}

// ---------------------------------------------------------------------------
// Kernel 3: conv3d 3x3x3 circular, implicit-GEMM MFMA, barrier-free tap loop.
// Wave w owns co block w*16..+16 (A-frags = coalesced global loads of Wt3,
// 3-deep register ring); B-frags from the 64 KB swizzled halo (staged once).
// ---------------------------------------------------------------------------
__global__ __launch_bounds__(256, 2) void conv_kernel(
    const __hip_bfloat16* __restrict__ omid,
    const __hip_bfloat16* __restrict__ Wt3,
    const float* __restrict__ bc,
    const float* __restrict__ xin,
    float* __restrict__ out) {
  __shared__ __hip_bfloat16 halo[512 * 64];   // 64 KB

  const int b    = blockIdx.y;
  const int x0   = (blockIdx.x >> 4) * 2;
  const int y0   = (blockIdx.x & 15) * 2;
  const int tid  = threadIdx.x;
  const int lane = tid & 63;
  const int w    = tid >> 6;
  const int quad = lane >> 4;
  const int l15  = lane & 15;

  // --- halo staging: 64 chunks x 1KB via global_load_lds ---
  {
    const __hip_bfloat16* src = omid + (size_t)b * MVOX * C_;
    #pragma unroll
    for (int n = 0; n < 16; ++n) {
      const int chunk = w * 16 + n;
      const int li = chunk >> 2;
      const int zb = (chunk & 3) * 8;
      const int gx = (x0 - 1 + (li >> 2)) & 31;
      const int gy = (y0 - 1 + (li & 3)) & 31;
      const __hip_bfloat16* gsrc = src + (size_t)(gx * 1024 + gy * 32 + zb) * C_ + lane * 8;
      __builtin_amdgcn_global_load_lds((gas_u32*)gsrc,
                                       (las_u32*)&halo[chunk * 512], 16, 0, 0);
    }
  }

  // --- weight register ring: prologue loads taps 0..2 ---
  bf16x8 wf[3][2];
  #pragma unroll
  for (int t = 0; t < 3; ++t)
    #pragma unroll
    for (int kh = 0; kh < 2; ++kh)
      wf[t][kh] = *(const bf16x8*)(Wt3 + (((t * 4 + w) * 2 + kh) << 9) + lane * 8);
  __syncthreads();

  f32x4 acc[4][2];
  #pragma unroll
  for (int ll = 0; ll < 4; ++ll)
    #pragma unroll
    for (int f = 0; f < 2; ++f)
      #pragma unroll
      for (int r = 0; r < 4; ++r) acc[ll][f][r] = 0.f;

  #pragma unroll
  for (int t = 0; t < 27; ++t) {
    const int dxy = t / 3, dz = t % 3;
    const int dx = dxy / 3, dy = dxy % 3;
    #pragma unroll
    for (int ll = 0; ll < 4; ++ll) {
      const int hline = ((ll >> 1) + dx) * 4 + ((ll & 1) + dy);
      bf16x8 bfr[2][2];
      #pragma unroll
      for (int f = 0; f < 2; ++f) {
        const int zs = (f * 16 + l15 + dz - 1) & 31;
        const int sw = zs & 7;
        #pragma unroll
        for (int kh = 0; kh < 2; ++kh) {
          const int a16 = (hline * 32 + zs) * 8 + ((kh * 4 + quad) ^ sw);
          bfr[f][kh] = *(const bf16x8*)&halo[a16 * 8];
        }
      }
      #pragma unroll
      for (int f = 0; f < 2; ++f)
        #pragma unroll
        for (int kh = 0; kh < 2; ++kh)
          acc[ll][f] = __builtin_amdgcn_mfma_f32_16x16x32_bf16(wf[t % 3][kh], bfr[f][kh],
                                                               acc[ll][f], 0, 0, 0);
    }
    if (t < 24) {
      #pragma unroll
      for (int kh = 0; kh < 2; ++kh)
        wf[t % 3][kh] = *(const bf16x8*)(Wt3 + ((((t + 3) * 4 + w) * 2 + kh) << 9) + lane * 8);
    }
  }

  // --- epilogue: relu(acc+bias) + residual ---
  #pragma unroll
  for (int ll = 0; ll < 4; ++ll) {
    const int gx = x0 + (ll >> 1), gy = y0 + (ll & 1);
    #pragma unroll
    for (int f = 0; f < 2; ++f) {
      const int z = f * 16 + l15;
      #pragma unroll
      for (int r = 0; r < 4; ++r) {
        const int co = w * 16 + quad * 4 + r;
        const size_t idx = ((size_t)(b * C_ + co)) * MVOX + gx * 1024 + gy * 32 + z;
        out[idx] = fmaxf(acc[ll][f][r] + bc[co], 0.f) + xin[idx];
      }
    }
  }
}

// ---------------------------------------------------------------------------
extern "C" void kernel_launch(void* const* d_in, const int* in_sizes, int n_in,
                              void* d_out, int out_size, void* d_ws, size_t ws_size,
                              hipStream_t stream) {
  const float* x   = (const float*)d_in[0];
  const float* mol = (const float*)d_in[1];
  const int*   bn  = (const int*)  d_in[2];
  const float* Wq  = (const float*)d_in[3];
  const float* bq  = (const float*)d_in[4];
  const float* Wk  = (const float*)d_in[5];
  const float* bk  = (const float*)d_in[6];
  const float* Wv  = (const float*)d_in[7];
  const float* bv  = (const float*)d_in[8];
  const float* Wo  = (const float*)d_in[9];
  const float* bo  = (const float*)d_in[10];
  const float* Wc  = (const float*)d_in[11];
  const float* bc  = (const float*)d_in[12];
  float* out = (float*)d_out;

  char* ws = (char*)d_ws;
  __hip_bfloat16* omid = (__hip_bfloat16*)ws;                     // 16,777,216 B
  float* kbuf = (float*)(ws + 16777216);                          // 65,536 B
  float* vbuf = kbuf + B_ * NATOM * C_;                           // 65,536 B
  __hip_bfloat16* Wt3 = (__hip_bfloat16*)(ws + 16908288);         // 221,184 B
  __hip_bfloat16* Wqb = (__hip_bfloat16*)(ws + 17129472);         // 8,192 B
  __hip_bfloat16* Wob = (__hip_bfloat16*)(ws + 17137664);         // 8,192 B

  wprep_kernel<<<dim3(464), 256, 0, stream>>>(Wc, Wq, Wo, Wt3, Wqb, Wob);
  kv_kernel<<<dim3(B_, 2), 256, 0, stream>>>(mol, Wk, bk, Wv, bv, kbuf, vbuf);
  attn_kernel<<<dim3(MVOX / 64, B_), 512, 0, stream>>>(x, kbuf, vbuf, bn, Wqb, bq, Wob, bo, omid);
  conv_kernel<<<dim3(256, B_), 256, 0, stream>>>(omid, Wt3, bc, x, out);
}

// Round 7
// 186.585 us; speedup vs baseline: 1.2016x; 1.2016x over previous
//
#include <hip/hip_runtime.h>
#include <hip/hip_bf16.h>

#define B_    4
#define C_    64
#define MVOX  32768      // 32*32*32
#define NATOM 64
#define EMB_  128

typedef __attribute__((ext_vector_type(8)))  __bf16 bf16x8;
typedef __attribute__((ext_vector_type(4)))  float  f32x4;
typedef __attribute__((ext_vector_type(16))) float  f32x16;
typedef __attribute__((ext_vector_type(8)))  unsigned short ushort8;

typedef __attribute__((address_space(1))) const unsigned int gas_u32;
typedef __attribute__((address_space(3))) unsigned int las_u32;

// ---------------------------------------------------------------------------
// Kernel 0: weight prep.
//  Wt4 (conv, 32x32 MFMA): [tap][coh][ks][lane][j] bf16,
//     co = coh*32+(lane&31), ci = ks*16+(lane>>5)*8+j  -> coalesced A-frags.
//  Wqb: [nf][kk][lane][j] = Wq[nf*16+(lane&15)][kk*32+(lane>>4)*8+j]/sqrt(8)
//  Wob: same layout from Wo, unscaled.
// ---------------------------------------------------------------------------
__global__ __launch_bounds__(256) void wprep_kernel(
    const float* __restrict__ Wc, const float* __restrict__ Wq,
    const float* __restrict__ Wo,
    __hip_bfloat16* __restrict__ Wt4, __hip_bfloat16* __restrict__ Wqb,
    __hip_bfloat16* __restrict__ Wob) {
  const int i = blockIdx.x * 256 + threadIdx.x;
  if (i < 110592) {                                   // conv weights
    const int tap = i >> 12;
    const int coh = (i >> 11) & 1;
    const int ks  = (i >> 9) & 3;
    const int l   = (i >> 3) & 63;
    const int j   = i & 7;
    const int co  = coh * 32 + (l & 31);
    const int ci  = ks * 16 + ((l >> 5) << 3) + j;
    Wt4[i] = __float2bfloat16(Wc[(co * C_ + ci) * 27 + tap]);
  } else if (i < 114688) {                            // Wq (scaled)
    const int i2 = i - 110592;
    const int nf = (i2 >> 10) & 3;
    const int kk = (i2 >> 9) & 1;
    const int l  = (i2 >> 3) & 63;
    const int j  = i2 & 7;
    const int co = nf * 16 + (l & 15);
    const int ci = kk * 32 + ((l >> 4) << 3) + j;
    Wqb[i2] = __float2bfloat16(Wq[co * C_ + ci] * 0.3535533905932738f);
  } else if (i < 118784) {                            // Wo
    const int i3 = i - 114688;
    const int nf = (i3 >> 10) & 3;
    const int kk = (i3 >> 9) & 1;
    const int l  = (i3 >> 3) & 63;
    const int j  = i3 & 7;
    const int co = nf * 16 + (l & 15);
    const int ci = kk * 32 + ((l >> 4) << 3) + j;
    Wob[i3] = __float2bfloat16(Wo[co * C_ + ci]);
  }
}

// ---------------------------------------------------------------------------
// Kernel 1: K/V projections (tiny)
// ---------------------------------------------------------------------------
__global__ __launch_bounds__(256) void kv_kernel(
    const float* __restrict__ mol,
    const float* __restrict__ Wk, const float* __restrict__ bk,
    const float* __restrict__ Wv, const float* __restrict__ bv,
    float* __restrict__ kout, float* __restrict__ vout) {
  __shared__ float smol[NATOM * EMB_];
  __shared__ float sw[C_ * EMB_];
  const int b = blockIdx.x;
  const bool is_v = (blockIdx.y == 1);
  const float* W    = is_v ? Wv : Wk;
  const float* bias = is_v ? bv : bk;
  float* out        = is_v ? vout : kout;

  for (int i = threadIdx.x; i < NATOM * EMB_; i += 256) {
    smol[i] = mol[b * NATOM * EMB_ + i];
    sw[i]   = W[i];
  }
  __syncthreads();
  for (int idx = threadIdx.x; idx < NATOM * C_; idx += 256) {
    const int a = idx >> 6, c = idx & 63;
    float acc = bias[c];
    #pragma unroll 8
    for (int e = 0; e < EMB_; ++e) acc += smol[a * EMB_ + e] * sw[c * EMB_ + e];
    out[b * NATOM * C_ + idx] = acc;
  }
}

// ---------------------------------------------------------------------------
// Kernel 2: fused Q-proj(MFMA) + ragged attention(VALU) + O-proj(MFMA) + ReLU.
// 512 threads = 8 waves. LDS 48 KB (sk doubles as os after a barrier) ->
// up to 3 blocks/CU. launch_bounds(512,2): 256-VGPR cap, NO spill (R5 lesson:
// the allocator spilled l[32]+frags to scratch = 270 MB writes/dispatch).
// Attention processes 4 chunks x 16 atoms to cut peak register pressure.
// ---------------------------------------------------------------------------
__global__ __launch_bounds__(512, 2) void attn_kernel(
    const float* __restrict__ x,
    const float* __restrict__ kbuf, const float* __restrict__ vbuf,
    const int* __restrict__ batch_nodes,
    const __hip_bfloat16* __restrict__ Wqb, const float* __restrict__ bq,
    const __hip_bfloat16* __restrict__ Wob, const float* __restrict__ bo,
    __hip_bfloat16* __restrict__ omid) {
  __shared__ float sk[NATOM * C_];   // 16 KB; becomes os after attention
  __shared__ float sv[NATOM * C_];   // 16 KB
  __shared__ float xq[64 * C_];      // 16 KB: x[c][vox] -> Q[vox][c] -> osb

  const int b    = blockIdx.y;
  const int m0   = blockIdx.x * 64;
  const int tid  = threadIdx.x;
  const int vox  = tid & 63;
  const int lane = tid & 63;
  const int w    = __builtin_amdgcn_readfirstlane(tid >> 6);   // 0..7
  const int quad = lane >> 4;
  const int l15  = lane & 15;
  const int vq   = w & 3;            // vox block for projections
  const int cq   = w >> 2;           // co half for projections

  // ---- stage x tile [c][vox] (16 KB) via global_load_lds ----
  #pragma unroll
  for (int j = 0; j < 2; ++j) {
    const int cidx = w * 2 + j;                  // 0..15
    const int c  = cidx * 4 + (lane >> 4);
    const int v4 = (lane & 15) * 4;
    const float* gsrc = x + (size_t)(b * C_ + c) * MVOX + m0 + v4;
    __builtin_amdgcn_global_load_lds((gas_u32*)gsrc,
                                     (las_u32*)&xq[cidx * 256], 16, 0, 0);
  }
  for (int i = tid; i < NATOM * C_; i += 512) {
    sk[i] = kbuf[b * NATOM * C_ + i];
    sv[i] = vbuf[b * NATOM * C_ + i];
  }
  __syncthreads();

  // ---- Q projection via MFMA: D[vox][co], wave = 16 vox x 32 co ----
  f32x4 qacc[2];
  {
    bf16x8 af[2];
    #pragma unroll
    for (int kk = 0; kk < 2; ++kk) {
      ushort8 au;
      #pragma unroll
      for (int j = 0; j < 8; ++j) {
        const int ci = kk * 32 + quad * 8 + j;
        __hip_bfloat16 hb = __float2bfloat16(xq[ci * 64 + vq * 16 + l15]);
        au[j] = *(unsigned short*)&hb;
      }
      af[kk] = __builtin_bit_cast(bf16x8, au);
    }
    #pragma unroll
    for (int nf2 = 0; nf2 < 2; ++nf2) {
      const int nf = cq * 2 + nf2;
      const float bqv = bq[nf * 16 + l15] * 0.3535533905932738f;
      qacc[nf2] = {bqv, bqv, bqv, bqv};
      #pragma unroll
      for (int kk = 0; kk < 2; ++kk) {
        const bf16x8 bf = *(const bf16x8*)(Wqb + (((nf * 2 + kk) << 6) + lane) * 8);
        qacc[nf2] = __builtin_amdgcn_mfma_f32_16x16x32_bf16(af[kk], bf, qacc[nf2], 0, 0, 0);
      }
    }
  }
  __syncthreads();   // all xq (x-phase) reads done

  // write Q to xq[vox][c] with 16B-chunk swizzle (c4 ^ (vox&15))
  #pragma unroll
  for (int nf2 = 0; nf2 < 2; ++nf2) {
    const int co = (cq * 2 + nf2) * 16 + l15;
    const int c4 = co >> 2, ce = co & 3;
    #pragma unroll
    for (int r = 0; r < 4; ++r) {
      const int vr = vq * 16 + quad * 4 + r;
      xq[vr * 64 + ((c4 ^ (vr & 15)) << 2) + ce] = qacc[nf2][r];
    }
  }
  __syncthreads();

  // ---- ragged attention (VALU), thread = (vox, head w), 4x16 atoms ----
  const int h = w;
  float qa[8];
  {
    const f32x4 q0 = *(const f32x4*)&xq[vox * 64 + (((h * 2)     ^ (vox & 15)) << 2)];
    const f32x4 q1 = *(const f32x4*)&xq[vox * 64 + (((h * 2 + 1) ^ (vox & 15)) << 2)];
    qa[0]=q0.x; qa[1]=q0.y; qa[2]=q0.z; qa[3]=q0.w;
    qa[4]=q1.x; qa[5]=q1.y; qa[6]=q1.z; qa[7]=q1.w;
  }
  const int nv = batch_nodes[b];
  float mrun = -1e30f, lsum = 0.f;
  float acc[8];
  #pragma unroll
  for (int d = 0; d < 8; ++d) acc[d] = 0.f;

  #pragma unroll 1
  for (int ch = 0; ch < 4; ++ch) {
    float l[16];
    float cmax = -1e30f;
    #pragma unroll
    for (int a = 0; a < 16; ++a) {
      const int atom = ch * 16 + a;
      const f32x4 k0 = *(const f32x4*)&sk[atom * C_ + h * 8];
      const f32x4 k1 = *(const f32x4*)&sk[atom * C_ + h * 8 + 4];
      float lg = qa[0]*k0.x + qa[1]*k0.y + qa[2]*k0.z + qa[3]*k0.w
               + qa[4]*k1.x + qa[5]*k1.y + qa[6]*k1.z + qa[7]*k1.w;
      lg = (atom < nv) ? lg : -1e30f;
      l[a] = lg;
      cmax = fmaxf(cmax, lg);
    }
    const float mnew = fmaxf(mrun, cmax);
    const float corr = __expf(mrun - mnew);
    lsum *= corr;
    #pragma unroll
    for (int d = 0; d < 8; ++d) acc[d] *= corr;
    #pragma unroll
    for (int a = 0; a < 16; ++a) {
      const int atom = ch * 16 + a;
      const float p = __expf(l[a] - mnew);
      lsum += p;
      const f32x4 v0 = *(const f32x4*)&sv[atom * C_ + h * 8];
      const f32x4 v1 = *(const f32x4*)&sv[atom * C_ + h * 8 + 4];
      acc[0] += p * v0.x;  acc[1] += p * v0.y;
      acc[2] += p * v0.z;  acc[3] += p * v0.w;
      acc[4] += p * v1.x;  acc[5] += p * v1.y;
      acc[6] += p * v1.z;  acc[7] += p * v1.w;
    }
    mrun = mnew;
  }
  const float inv = 1.f / lsum;
  __syncthreads();   // all sk/sv reads done -> sk becomes os

  // write attn out to os (=sk) [vox][c] swizzled
  float* os = sk;
  #pragma unroll
  for (int i = 0; i < 2; ++i) {
    const int c4 = h * 2 + i;
    f32x4 val;
    val.x = acc[i * 4 + 0] * inv; val.y = acc[i * 4 + 1] * inv;
    val.z = acc[i * 4 + 2] * inv; val.w = acc[i * 4 + 3] * inv;
    *(f32x4*)&os[vox * 64 + ((c4 ^ (vox & 15)) << 2)] = val;
  }
  __syncthreads();

  // ---- O projection via MFMA + ReLU -> bf16 exchange in xq ----
  {
    bf16x8 af[2];
    #pragma unroll
    for (int kk = 0; kk < 2; ++kk) {
      ushort8 au;
      #pragma unroll
      for (int j = 0; j < 8; ++j) {
        const int ci = kk * 32 + quad * 8 + j;
        const int c4 = ci >> 2;
        const float f = os[(vq * 16 + l15) * 64 + ((c4 ^ l15) << 2) + (ci & 3)];
        __hip_bfloat16 hb = __float2bfloat16(f);
        au[j] = *(unsigned short*)&hb;
      }
      af[kk] = __builtin_bit_cast(bf16x8, au);
    }
    f32x4 oacc[2];
    #pragma unroll
    for (int nf2 = 0; nf2 < 2; ++nf2) {
      const int nf = cq * 2 + nf2;
      const float bov = bo[nf * 16 + l15];
      oacc[nf2] = {bov, bov, bov, bov};
      #pragma unroll
      for (int kk = 0; kk < 2; ++kk) {
        const bf16x8 bf = *(const bf16x8*)(Wob + (((nf * 2 + kk) << 6) + lane) * 8);
        oacc[nf2] = __builtin_amdgcn_mfma_f32_16x16x32_bf16(af[kk], bf, oacc[nf2], 0, 0, 0);
      }
    }
    // relu + pack bf16 into xq alias at chunk' = chunk ^ (vox&7)
    unsigned short* osb = (unsigned short*)xq;
    #pragma unroll
    for (int nf2 = 0; nf2 < 2; ++nf2) {
      const int co = (cq * 2 + nf2) * 16 + l15;
      #pragma unroll
      for (int r = 0; r < 4; ++r) {
        const int vr = vq * 16 + quad * 4 + r;
        __hip_bfloat16 hb = __float2bfloat16(fmaxf(oacc[nf2][r], 0.f));
        osb[vr * 64 + (((co >> 3) ^ (vr & 7)) << 3) + (co & 7)] = *(unsigned short*)&hb;
      }
    }
  }
  __syncthreads();

  // ---- coalesced store: xq alias already holds conv's swizzled layout ----
  *(ushort8*)(omid + (size_t)(b * MVOX + m0) * C_ + tid * 8) =
      *(const ushort8*)&((unsigned short*)xq)[tid * 8];
}

// ---------------------------------------------------------------------------
// Kernel 3: conv3d 3x3x3 circular, implicit-GEMM with mfma_f32_32x32x16_bf16
// (2x MACs per fragment vs 16x16x32 -> halves LDS-read issue pressure).
// Wave w: coh = w&1 (32 co), lp = w>>1 (x-line); covers 2 y-lines x 32 z.
// A-frags: coalesced global loads of Wt4, 3-deep register ring, no barriers.
// B-frags: 64 KB swizzled halo (staged once via global_load_lds).
// ---------------------------------------------------------------------------
__global__ __launch_bounds__(256, 2) void conv_kernel(
    const __hip_bfloat16* __restrict__ omid,
    const __hip_bfloat16* __restrict__ Wt4,
    const float* __restrict__ bc,
    const float* __restrict__ xin,
    float* __restrict__ out) {
  __shared__ __hip_bfloat16 halo[512 * 64];   // 64 KB

  const int b    = blockIdx.y;
  const int x0   = (blockIdx.x >> 4) * 2;
  const int y0   = (blockIdx.x & 15) * 2;
  const int tid  = threadIdx.x;
  const int lane = tid & 63;
  const int w    = tid >> 6;
  const int coh  = w & 1;
  const int lp   = w >> 1;

  // --- halo staging: 64 chunks x 1KB via global_load_lds ---
  {
    const __hip_bfloat16* src = omid + (size_t)b * MVOX * C_;
    #pragma unroll
    for (int n = 0; n < 16; ++n) {
      const int chunk = w * 16 + n;
      const int li = chunk >> 2;
      const int zb = (chunk & 3) * 8;
      const int gx = (x0 - 1 + (li >> 2)) & 31;
      const int gy = (y0 - 1 + (li & 3)) & 31;
      const __hip_bfloat16* gsrc = src + (size_t)(gx * 1024 + gy * 32 + zb) * C_ + lane * 8;
      __builtin_amdgcn_global_load_lds((gas_u32*)gsrc,
                                       (las_u32*)&halo[chunk * 512], 16, 0, 0);
    }
  }

  // --- weight register ring: prologue loads taps 0,1 ---
  bf16x8 wf[3][4];
  #pragma unroll
  for (int t = 0; t < 2; ++t)
    #pragma unroll
    for (int ks = 0; ks < 4; ++ks)
      wf[t][ks] = *(const bf16x8*)(Wt4 + (((t * 2 + coh) * 4 + ks) << 9) + lane * 8);
  __syncthreads();

  f32x16 acc[2];
  #pragma unroll
  for (int i = 0; i < 2; ++i)
    #pragma unroll
    for (int r = 0; r < 16; ++r) acc[i][r] = 0.f;

  #pragma unroll
  for (int t = 0; t < 27; ++t) {
    if (t < 25) {
      #pragma unroll
      for (int ks = 0; ks < 4; ++ks)
        wf[(t + 2) % 3][ks] =
            *(const bf16x8*)(Wt4 + ((((t + 2) * 2 + coh) * 4 + ks) << 9) + lane * 8);
    }
    const int dxy = t / 3, dz = t % 3;
    const int dx = dxy / 3, dy = dxy % 3;
    const int zp = ((lane & 31) + dz + 31) & 31;   // input z for this lane
    const int sw = zp & 7;
    #pragma unroll
    for (int ks = 0; ks < 4; ++ks) {
      const int phys = (ks * 2 + (lane >> 5)) ^ sw;
      #pragma unroll
      for (int i = 0; i < 2; ++i) {
        const int hline = (lp + dx) * 4 + (i + dy);
        const bf16x8 bfr = *(const bf16x8*)&halo[((hline * 32 + zp) * 8 + phys) * 8];
        acc[i] = __builtin_amdgcn_mfma_f32_32x32x16_bf16(wf[t % 3][ks], bfr, acc[i], 0, 0, 0);
      }
    }
  }

  // --- epilogue: relu(acc+bias) + residual ---
  const int z = lane & 31;
  #pragma unroll
  for (int i = 0; i < 2; ++i) {
    const int gx = x0 + lp, gy = y0 + i;
    #pragma unroll
    for (int r = 0; r < 16; ++r) {
      const int co = coh * 32 + (r & 3) + 8 * (r >> 2) + 4 * (lane >> 5);
      const size_t idx = ((size_t)(b * C_ + co)) * MVOX + gx * 1024 + gy * 32 + z;
      out[idx] = fmaxf(acc[i][r] + bc[co], 0.f) + xin[idx];
    }
  }
}

// ---------------------------------------------------------------------------
extern "C" void kernel_launch(void* const* d_in, const int* in_sizes, int n_in,
                              void* d_out, int out_size, void* d_ws, size_t ws_size,
                              hipStream_t stream) {
  const float* x   = (const float*)d_in[0];
  const float* mol = (const float*)d_in[1];
  const int*   bn  = (const int*)  d_in[2];
  const float* Wq  = (const float*)d_in[3];
  const float* bq  = (const float*)d_in[4];
  const float* Wk  = (const float*)d_in[5];
  const float* bk  = (const float*)d_in[6];
  const float* Wv  = (const float*)d_in[7];
  const float* bv  = (const float*)d_in[8];
  const float* Wo  = (const float*)d_in[9];
  const float* bo  = (const float*)d_in[10];
  const float* Wc  = (const float*)d_in[11];
  const float* bc  = (const float*)d_in[12];
  float* out = (float*)d_out;

  char* ws = (char*)d_ws;
  __hip_bfloat16* omid = (__hip_bfloat16*)ws;                     // 16,777,216 B
  float* kbuf = (float*)(ws + 16777216);                          // 65,536 B
  float* vbuf = kbuf + B_ * NATOM * C_;                           // 65,536 B
  __hip_bfloat16* Wt4 = (__hip_bfloat16*)(ws + 16908288);         // 221,184 B
  __hip_bfloat16* Wqb = (__hip_bfloat16*)(ws + 17129472);         // 8,192 B
  __hip_bfloat16* Wob = (__hip_bfloat16*)(ws + 17137664);         // 8,192 B

  wprep_kernel<<<dim3(464), 256, 0, stream>>>(Wc, Wq, Wo, Wt4, Wqb, Wob);
  kv_kernel<<<dim3(B_, 2), 256, 0, stream>>>(mol, Wk, bk, Wv, bv, kbuf, vbuf);
  attn_kernel<<<dim3(MVOX / 64, B_), 512, 0, stream>>>(x, kbuf, vbuf, bn, Wqb, bq, Wob, bo, omid);
  conv_kernel<<<dim3(256, B_), 256, 0, stream>>>(omid, Wt4, bc, x, out);
}

// Round 8
// 153.391 us; speedup vs baseline: 1.4616x; 1.2164x over previous
//
#include <hip/hip_runtime.h>
#include <hip/hip_bf16.h>

#define B_    4
#define C_    64
#define MVOX  32768      // 32*32*32
#define NATOM 64
#define EMB_  128

typedef __attribute__((ext_vector_type(8)))  __bf16 bf16x8;
typedef __attribute__((ext_vector_type(4)))  float  f32x4;
typedef __attribute__((ext_vector_type(16))) float  f32x16;
typedef __attribute__((ext_vector_type(8)))  unsigned short ushort8;

typedef __attribute__((address_space(1))) const unsigned int gas_u32;
typedef __attribute__((address_space(3))) unsigned int las_u32;

// ---------------------------------------------------------------------------
// Kernel 0: weight prep.
//  Wt4 (conv, 32x32 MFMA): [tap][coh][ks][lane][j] bf16,
//     co = coh*32+(lane&31), ci = ks*16+(lane>>5)*8+j  -> coalesced A-frags.
//  Wqb: [nf][kk][lane][j] = Wq[nf*16+(lane&15)][kk*32+(lane>>4)*8+j]/sqrt(8)
//  Wob: same layout from Wo, unscaled.
// ---------------------------------------------------------------------------
__global__ __launch_bounds__(256) void wprep_kernel(
    const float* __restrict__ Wc, const float* __restrict__ Wq,
    const float* __restrict__ Wo,
    __hip_bfloat16* __restrict__ Wt4, __hip_bfloat16* __restrict__ Wqb,
    __hip_bfloat16* __restrict__ Wob) {
  const int i = blockIdx.x * 256 + threadIdx.x;
  if (i < 110592) {                                   // conv weights
    const int tap = i >> 12;
    const int coh = (i >> 11) & 1;
    const int ks  = (i >> 9) & 3;
    const int l   = (i >> 3) & 63;
    const int j   = i & 7;
    const int co  = coh * 32 + (l & 31);
    const int ci  = ks * 16 + ((l >> 5) << 3) + j;
    Wt4[i] = __float2bfloat16(Wc[(co * C_ + ci) * 27 + tap]);
  } else if (i < 114688) {                            // Wq (scaled)
    const int i2 = i - 110592;
    const int nf = (i2 >> 10) & 3;
    const int kk = (i2 >> 9) & 1;
    const int l  = (i2 >> 3) & 63;
    const int j  = i2 & 7;
    const int co = nf * 16 + (l & 15);
    const int ci = kk * 32 + ((l >> 4) << 3) + j;
    Wqb[i2] = __float2bfloat16(Wq[co * C_ + ci] * 0.3535533905932738f);
  } else if (i < 118784) {                            // Wo
    const int i3 = i - 114688;
    const int nf = (i3 >> 10) & 3;
    const int kk = (i3 >> 9) & 1;
    const int l  = (i3 >> 3) & 63;
    const int j  = i3 & 7;
    const int co = nf * 16 + (l & 15);
    const int ci = kk * 32 + ((l >> 4) << 3) + j;
    Wob[i3] = __float2bfloat16(Wo[co * C_ + ci]);
  }
}

// ---------------------------------------------------------------------------
// Kernel 1: K/V projections (tiny)
// ---------------------------------------------------------------------------
__global__ __launch_bounds__(256) void kv_kernel(
    const float* __restrict__ mol,
    const float* __restrict__ Wk, const float* __restrict__ bk,
    const float* __restrict__ Wv, const float* __restrict__ bv,
    float* __restrict__ kout, float* __restrict__ vout) {
  __shared__ float smol[NATOM * EMB_];
  __shared__ float sw[C_ * EMB_];
  const int b = blockIdx.x;
  const bool is_v = (blockIdx.y == 1);
  const float* W    = is_v ? Wv : Wk;
  const float* bias = is_v ? bv : bk;
  float* out        = is_v ? vout : kout;

  for (int i = threadIdx.x; i < NATOM * EMB_; i += 256) {
    smol[i] = mol[b * NATOM * EMB_ + i];
    sw[i]   = W[i];
  }
  __syncthreads();
  for (int idx = threadIdx.x; idx < NATOM * C_; idx += 256) {
    const int a = idx >> 6, c = idx & 63;
    float acc = bias[c];
    #pragma unroll 8
    for (int e = 0; e < EMB_; ++e) acc += smol[a * EMB_ + e] * sw[c * EMB_ + e];
    out[b * NATOM * C_ + idx] = acc;
  }
}

// ---------------------------------------------------------------------------
// Kernel 2: fused Q-proj(MFMA) + ragged attention(VALU) + O-proj(MFMA) + ReLU.
// 512 threads = 8 waves. launch_bounds(512,8): VGPR cap 64 -> stays in the
// 8-waves/SIMD HW register class (m69 granularity: 68 regs rounds to 128 and
// HALVES occupancy - the R7 regression). Ragged early-exit: only ceil(nv/8)
// chunks of 8 atoms are processed (nv uniform per block).
// ---------------------------------------------------------------------------
__global__ __launch_bounds__(512, 8) void attn_kernel(
    const float* __restrict__ x,
    const float* __restrict__ kbuf, const float* __restrict__ vbuf,
    const int* __restrict__ batch_nodes,
    const __hip_bfloat16* __restrict__ Wqb, const float* __restrict__ bq,
    const __hip_bfloat16* __restrict__ Wob, const float* __restrict__ bo,
    __hip_bfloat16* __restrict__ omid) {
  __shared__ float sk[NATOM * C_];   // 16 KB; becomes os after attention
  __shared__ float sv[NATOM * C_];   // 16 KB
  __shared__ float xq[64 * C_];      // 16 KB: x[c][vox] -> Q[vox][c] -> osb

  const int b    = blockIdx.y;
  const int m0   = blockIdx.x * 64;
  const int tid  = threadIdx.x;
  const int vox  = tid & 63;
  const int lane = tid & 63;
  const int w    = __builtin_amdgcn_readfirstlane(tid >> 6);   // 0..7
  const int quad = lane >> 4;
  const int l15  = lane & 15;
  const int vq   = w & 3;            // vox block for projections
  const int cq   = w >> 2;           // co half for projections

  // ---- stage x tile [c][vox] (16 KB) via global_load_lds ----
  #pragma unroll
  for (int j = 0; j < 2; ++j) {
    const int cidx = w * 2 + j;                  // 0..15
    const int c  = cidx * 4 + (lane >> 4);
    const int v4 = (lane & 15) * 4;
    const float* gsrc = x + (size_t)(b * C_ + c) * MVOX + m0 + v4;
    __builtin_amdgcn_global_load_lds((gas_u32*)gsrc,
                                     (las_u32*)&xq[cidx * 256], 16, 0, 0);
  }
  for (int i = tid; i < NATOM * C_; i += 512) {
    sk[i] = kbuf[b * NATOM * C_ + i];
    sv[i] = vbuf[b * NATOM * C_ + i];
  }
  __syncthreads();

  // ---- Q projection via MFMA: D[vox][co], wave = 16 vox x 32 co ----
  f32x4 qacc[2];
  {
    bf16x8 af[2];
    #pragma unroll
    for (int kk = 0; kk < 2; ++kk) {
      ushort8 au;
      #pragma unroll
      for (int j = 0; j < 8; ++j) {
        const int ci = kk * 32 + quad * 8 + j;
        __hip_bfloat16 hb = __float2bfloat16(xq[ci * 64 + vq * 16 + l15]);
        au[j] = *(unsigned short*)&hb;
      }
      af[kk] = __builtin_bit_cast(bf16x8, au);
    }
    #pragma unroll
    for (int nf2 = 0; nf2 < 2; ++nf2) {
      const int nf = cq * 2 + nf2;
      const float bqv = bq[nf * 16 + l15] * 0.3535533905932738f;
      qacc[nf2] = {bqv, bqv, bqv, bqv};
      #pragma unroll
      for (int kk = 0; kk < 2; ++kk) {
        const bf16x8 bf = *(const bf16x8*)(Wqb + (((nf * 2 + kk) << 6) + lane) * 8);
        qacc[nf2] = __builtin_amdgcn_mfma_f32_16x16x32_bf16(af[kk], bf, qacc[nf2], 0, 0, 0);
      }
    }
  }
  __syncthreads();   // all xq (x-phase) reads done

  // write Q to xq[vox][c] with 16B-chunk swizzle (c4 ^ (vox&15))
  #pragma unroll
  for (int nf2 = 0; nf2 < 2; ++nf2) {
    const int co = (cq * 2 + nf2) * 16 + l15;
    const int c4 = co >> 2, ce = co & 3;
    #pragma unroll
    for (int r = 0; r < 4; ++r) {
      const int vr = vq * 16 + quad * 4 + r;
      xq[vr * 64 + ((c4 ^ (vr & 15)) << 2) + ce] = qacc[nf2][r];
    }
  }
  __syncthreads();

  // ---- ragged attention (VALU), thread = (vox, head w), chunks of 8 ----
  const int h = w;
  float qa[8];
  {
    const f32x4 q0 = *(const f32x4*)&xq[vox * 64 + (((h * 2)     ^ (vox & 15)) << 2)];
    const f32x4 q1 = *(const f32x4*)&xq[vox * 64 + (((h * 2 + 1) ^ (vox & 15)) << 2)];
    qa[0]=q0.x; qa[1]=q0.y; qa[2]=q0.z; qa[3]=q0.w;
    qa[4]=q1.x; qa[5]=q1.y; qa[6]=q1.z; qa[7]=q1.w;
  }
  const int nv    = batch_nodes[b];   // uniform, 1..64
  const int nfull = nv >> 3;
  const int nrem  = nv & 7;
  float mrun = -1e30f, lsum = 0.f;
  float acc[8];
  #pragma unroll
  for (int d = 0; d < 8; ++d) acc[d] = 0.f;

  #pragma unroll 1
  for (int ch = 0; ch < nfull; ++ch) {      // full 8-atom chunks, unmasked
    float l[8];
    float cmax = -1e30f;
    #pragma unroll
    for (int a = 0; a < 8; ++a) {
      const int atom = ch * 8 + a;
      const f32x4 k0 = *(const f32x4*)&sk[atom * C_ + h * 8];
      const f32x4 k1 = *(const f32x4*)&sk[atom * C_ + h * 8 + 4];
      const float lg = qa[0]*k0.x + qa[1]*k0.y + qa[2]*k0.z + qa[3]*k0.w
                     + qa[4]*k1.x + qa[5]*k1.y + qa[6]*k1.z + qa[7]*k1.w;
      l[a] = lg;
      cmax = fmaxf(cmax, lg);
    }
    const float mnew = fmaxf(mrun, cmax);
    const float corr = __expf(mrun - mnew);
    lsum *= corr;
    #pragma unroll
    for (int d = 0; d < 8; ++d) acc[d] *= corr;
    #pragma unroll
    for (int a = 0; a < 8; ++a) {
      const int atom = ch * 8 + a;
      const float p = __expf(l[a] - mnew);
      lsum += p;
      const f32x4 v0 = *(const f32x4*)&sv[atom * C_ + h * 8];
      const f32x4 v1 = *(const f32x4*)&sv[atom * C_ + h * 8 + 4];
      acc[0] += p * v0.x;  acc[1] += p * v0.y;
      acc[2] += p * v0.z;  acc[3] += p * v0.w;
      acc[4] += p * v1.x;  acc[5] += p * v1.y;
      acc[6] += p * v1.z;  acc[7] += p * v1.w;
    }
    mrun = mnew;
  }
  if (nrem) {                               // masked tail chunk
    float l[8];
    float cmax = -1e30f;
    #pragma unroll
    for (int a = 0; a < 8; ++a) {
      const int atom = nfull * 8 + a;
      const f32x4 k0 = *(const f32x4*)&sk[atom * C_ + h * 8];
      const f32x4 k1 = *(const f32x4*)&sk[atom * C_ + h * 8 + 4];
      float lg = qa[0]*k0.x + qa[1]*k0.y + qa[2]*k0.z + qa[3]*k0.w
               + qa[4]*k1.x + qa[5]*k1.y + qa[6]*k1.z + qa[7]*k1.w;
      lg = (a < nrem) ? lg : -1e30f;
      l[a] = lg;
      cmax = fmaxf(cmax, lg);
    }
    const float mnew = fmaxf(mrun, cmax);
    const float corr = __expf(mrun - mnew);
    lsum *= corr;
    #pragma unroll
    for (int d = 0; d < 8; ++d) acc[d] *= corr;
    #pragma unroll
    for (int a = 0; a < 8; ++a) {
      const int atom = nfull * 8 + a;
      const float p = __expf(l[a] - mnew);   // exact 0 for masked atoms
      lsum += p;
      const f32x4 v0 = *(const f32x4*)&sv[atom * C_ + h * 8];
      const f32x4 v1 = *(const f32x4*)&sv[atom * C_ + h * 8 + 4];
      acc[0] += p * v0.x;  acc[1] += p * v0.y;
      acc[2] += p * v0.z;  acc[3] += p * v0.w;
      acc[4] += p * v1.x;  acc[5] += p * v1.y;
      acc[6] += p * v1.z;  acc[7] += p * v1.w;
    }
  }
  const float inv = 1.f / lsum;
  __syncthreads();   // all sk/sv reads done -> sk becomes os

  // write attn out to os (=sk) [vox][c] swizzled
  float* os = sk;
  #pragma unroll
  for (int i = 0; i < 2; ++i) {
    const int c4 = h * 2 + i;
    f32x4 val;
    val.x = acc[i * 4 + 0] * inv; val.y = acc[i * 4 + 1] * inv;
    val.z = acc[i * 4 + 2] * inv; val.w = acc[i * 4 + 3] * inv;
    *(f32x4*)&os[vox * 64 + ((c4 ^ (vox & 15)) << 2)] = val;
  }
  __syncthreads();

  // ---- O projection via MFMA + ReLU -> bf16 exchange in xq ----
  {
    bf16x8 af[2];
    #pragma unroll
    for (int kk = 0; kk < 2; ++kk) {
      ushort8 au;
      #pragma unroll
      for (int j = 0; j < 8; ++j) {
        const int ci = kk * 32 + quad * 8 + j;
        const int c4 = ci >> 2;
        const float f = os[(vq * 16 + l15) * 64 + ((c4 ^ l15) << 2) + (ci & 3)];
        __hip_bfloat16 hb = __float2bfloat16(f);
        au[j] = *(unsigned short*)&hb;
      }
      af[kk] = __builtin_bit_cast(bf16x8, au);
    }
    f32x4 oacc[2];
    #pragma unroll
    for (int nf2 = 0; nf2 < 2; ++nf2) {
      const int nf = cq * 2 + nf2;
      const float bov = bo[nf * 16 + l15];
      oacc[nf2] = {bov, bov, bov, bov};
      #pragma unroll
      for (int kk = 0; kk < 2; ++kk) {
        const bf16x8 bf = *(const bf16x8*)(Wob + (((nf * 2 + kk) << 6) + lane) * 8);
        oacc[nf2] = __builtin_amdgcn_mfma_f32_16x16x32_bf16(af[kk], bf, oacc[nf2], 0, 0, 0);
      }
    }
    // relu + pack bf16 into xq alias at chunk' = chunk ^ (vox&7)
    unsigned short* osb = (unsigned short*)xq;
    #pragma unroll
    for (int nf2 = 0; nf2 < 2; ++nf2) {
      const int co = (cq * 2 + nf2) * 16 + l15;
      #pragma unroll
      for (int r = 0; r < 4; ++r) {
        const int vr = vq * 16 + quad * 4 + r;
        __hip_bfloat16 hb = __float2bfloat16(fmaxf(oacc[nf2][r], 0.f));
        osb[vr * 64 + (((co >> 3) ^ (vr & 7)) << 3) + (co & 7)] = *(unsigned short*)&hb;
      }
    }
  }
  __syncthreads();

  // ---- coalesced store: xq alias already holds conv's swizzled layout ----
  *(ushort8*)(omid + (size_t)(b * MVOX + m0) * C_ + tid * 8) =
      *(const ushort8*)&((unsigned short*)xq)[tid * 8];
}

// ---------------------------------------------------------------------------
// Kernel 3: conv3d 3x3x3 circular, implicit-GEMM mfma_f32_32x32x16_bf16.
// Tap-pipelined: ALL 8 B-fragments of tap t+1 are ds_read-issued BEFORE the
// 8 MFMAs of tap t (double-buffered in regs) -> compiler emits lgkmcnt(8),
// LDS latency hides under MFMA. Weights: 3-deep global register ring.
// ---------------------------------------------------------------------------
#define LOADB(dst, DX, DY, DZ)                                              \
  {                                                                         \
    const int zp_ = ((lane & 31) + (DZ) + 31) & 31;                         \
    const int sw_ = zp_ & 7;                                                \
    _Pragma("unroll")                                                       \
    for (int ks_ = 0; ks_ < 4; ++ks_) {                                     \
      const int phys_ = (ks_ * 2 + (lane >> 5)) ^ sw_;                      \
      _Pragma("unroll")                                                     \
      for (int i_ = 0; i_ < 2; ++i_) {                                      \
        const int hl_ = (lp + (DX)) * 4 + (i_ + (DY));                      \
        (dst)[i_ * 4 + ks_] =                                               \
            *(const bf16x8*)&halo[((hl_ * 32 + zp_) * 8 + phys_) * 8];      \
      }                                                                     \
    }                                                                       \
  }

#define LOADW(T2)                                                           \
  _Pragma("unroll")                                                         \
  for (int ks_ = 0; ks_ < 4; ++ks_)                                         \
    wf[(T2) % 3][ks_] =                                                     \
        *(const bf16x8*)(Wt4 + ((((T2) * 2 + coh) * 4 + ks_) << 9) + lane * 8);

#define DOMFMA(src, T)                                                      \
  _Pragma("unroll")                                                         \
  for (int ks_ = 0; ks_ < 4; ++ks_)                                         \
    _Pragma("unroll")                                                       \
    for (int i_ = 0; i_ < 2; ++i_)                                          \
      acc[i_] = __builtin_amdgcn_mfma_f32_32x32x16_bf16(                    \
          wf[(T) % 3][ks_], (src)[i_ * 4 + ks_], acc[i_], 0, 0, 0);

__global__ __launch_bounds__(256, 2) void conv_kernel(
    const __hip_bfloat16* __restrict__ omid,
    const __hip_bfloat16* __restrict__ Wt4,
    const float* __restrict__ bc,
    const float* __restrict__ xin,
    float* __restrict__ out) {
  __shared__ __hip_bfloat16 halo[512 * 64];   // 64 KB

  const int b    = blockIdx.y;
  const int x0   = (blockIdx.x >> 4) * 2;
  const int y0   = (blockIdx.x & 15) * 2;
  const int tid  = threadIdx.x;
  const int lane = tid & 63;
  const int w    = tid >> 6;
  const int coh  = w & 1;
  const int lp   = w >> 1;

  // --- halo staging: 64 chunks x 1KB via global_load_lds ---
  {
    const __hip_bfloat16* src = omid + (size_t)b * MVOX * C_;
    #pragma unroll
    for (int n = 0; n < 16; ++n) {
      const int chunk = w * 16 + n;
      const int li = chunk >> 2;
      const int zb = (chunk & 3) * 8;
      const int gx = (x0 - 1 + (li >> 2)) & 31;
      const int gy = (y0 - 1 + (li & 3)) & 31;
      const __hip_bfloat16* gsrc = src + (size_t)(gx * 1024 + gy * 32 + zb) * C_ + lane * 8;
      __builtin_amdgcn_global_load_lds((gas_u32*)gsrc,
                                       (las_u32*)&halo[chunk * 512], 16, 0, 0);
    }
  }

  // --- weight register ring: prologue loads taps 0,1 ---
  bf16x8 wf[3][4];
  LOADW(0);
  LOADW(1);
  __syncthreads();   // halo staged (drains vmcnt)

  f32x16 acc[2];
  #pragma unroll
  for (int i = 0; i < 2; ++i)
    #pragma unroll
    for (int r = 0; r < 16; ++r) acc[i][r] = 0.f;

  bf16x8 bA[8], bB[8];
  LOADB(bA, 0, 0, 0);   // tap 0

  #pragma unroll
  for (int t = 0; t < 27; ++t) {
    const int dxn = (t + 1) / 9, dyn = ((t + 1) / 3) % 3, dzn = (t + 1) % 3;
    if ((t & 1) == 0) {
      if (t < 26) LOADB(bB, dxn, dyn, dzn);
      if (t < 25) LOADW(t + 2);
      DOMFMA(bA, t);
    } else {
      if (t < 26) LOADB(bA, dxn, dyn, dzn);
      if (t < 25) LOADW(t + 2);
      DOMFMA(bB, t);
    }
  }

  // --- epilogue: relu(acc+bias) + residual ---
  const int z = lane & 31;
  #pragma unroll
  for (int i = 0; i < 2; ++i) {
    const int gx = x0 + lp, gy = y0 + i;
    #pragma unroll
    for (int r = 0; r < 16; ++r) {
      const int co = coh * 32 + (r & 3) + 8 * (r >> 2) + 4 * (lane >> 5);
      const size_t idx = ((size_t)(b * C_ + co)) * MVOX + gx * 1024 + gy * 32 + z;
      out[idx] = fmaxf(acc[i][r] + bc[co], 0.f) + xin[idx];
    }
  }
}

// ---------------------------------------------------------------------------
extern "C" void kernel_launch(void* const* d_in, const int* in_sizes, int n_in,
                              void* d_out, int out_size, void* d_ws, size_t ws_size,
                              hipStream_t stream) {
  const float* x   = (const float*)d_in[0];
  const float* mol = (const float*)d_in[1];
  const int*   bn  = (const int*)  d_in[2];
  const float* Wq  = (const float*)d_in[3];
  const float* bq  = (const float*)d_in[4];
  const float* Wk  = (const float*)d_in[5];
  const float* bk  = (const float*)d_in[6];
  const float* Wv  = (const float*)d_in[7];
  const float* bv  = (const float*)d_in[8];
  const float* Wo  = (const float*)d_in[9];
  const float* bo  = (const float*)d_in[10];
  const float* Wc  = (const float*)d_in[11];
  const float* bc  = (const float*)d_in[12];
  float* out = (float*)d_out;

  char* ws = (char*)d_ws;
  __hip_bfloat16* omid = (__hip_bfloat16*)ws;                     // 16,777,216 B
  float* kbuf = (float*)(ws + 16777216);                          // 65,536 B
  float* vbuf = kbuf + B_ * NATOM * C_;                           // 65,536 B
  __hip_bfloat16* Wt4 = (__hip_bfloat16*)(ws + 16908288);         // 221,184 B
  __hip_bfloat16* Wqb = (__hip_bfloat16*)(ws + 17129472);         // 8,192 B
  __hip_bfloat16* Wob = (__hip_bfloat16*)(ws + 17137664);         // 8,192 B

  wprep_kernel<<<dim3(464), 256, 0, stream>>>(Wc, Wq, Wo, Wt4, Wqb, Wob);
  kv_kernel<<<dim3(B_, 2), 256, 0, stream>>>(mol, Wk, bk, Wv, bv, kbuf, vbuf);
  attn_kernel<<<dim3(MVOX / 64, B_), 512, 0, stream>>>(x, kbuf, vbuf, bn, Wqb, bq, Wob, bo, omid);
  conv_kernel<<<dim3(256, B_), 256, 0, stream>>>(omid, Wt4, bc, x, out);
}

// Round 9
// 95.695 us; speedup vs baseline: 2.3429x; 1.6029x over previous
//
#include <hip/hip_runtime.h>
#include <hip/hip_bf16.h>

#define B_    4
#define C_    64
#define MVOX  32768      // 32*32*32
#define NATOM 64
#define EMB_  128

typedef __attribute__((ext_vector_type(8)))  __bf16 bf16x8;
typedef __attribute__((ext_vector_type(4)))  float  f32x4;
typedef __attribute__((ext_vector_type(16))) float  f32x16;
typedef __attribute__((ext_vector_type(8)))  unsigned short ushort8;

typedef __attribute__((address_space(1))) const unsigned int gas_u32;
typedef __attribute__((address_space(3))) unsigned int las_u32;

// ---------------------------------------------------------------------------
// Kernel 0: weight prep.
//  Wt4 (conv, 32x32 MFMA): [tap][coh][ks][lane][j] bf16,
//     co = coh*32+(lane&31), ci = ks*16+(lane>>5)*8+j  -> coalesced A-frags.
//  Wqb: [nf][kk][lane][j] = Wq[nf*16+(lane&15)][kk*32+(lane>>4)*8+j]/sqrt(8)
//  Wob: same layout from Wo, unscaled.
//  Wkb/Wvb (kv, 32x32 MFMA B-frags): [ch][kk][lane][j] =
//     W[ch*32+(lane&31)][kk*16+(lane>>5)*8+j]
// ---------------------------------------------------------------------------
__global__ __launch_bounds__(256) void wprep_kernel(
    const float* __restrict__ Wc, const float* __restrict__ Wq,
    const float* __restrict__ Wo, const float* __restrict__ Wk,
    const float* __restrict__ Wv,
    __hip_bfloat16* __restrict__ Wt4, __hip_bfloat16* __restrict__ Wqb,
    __hip_bfloat16* __restrict__ Wob, __hip_bfloat16* __restrict__ Wkb,
    __hip_bfloat16* __restrict__ Wvb) {
  const int i = blockIdx.x * 256 + threadIdx.x;
  if (i < 110592) {                                   // conv weights
    const int tap = i >> 12;
    const int coh = (i >> 11) & 1;
    const int ks  = (i >> 9) & 3;
    const int l   = (i >> 3) & 63;
    const int j   = i & 7;
    const int co  = coh * 32 + (l & 31);
    const int ci  = ks * 16 + ((l >> 5) << 3) + j;
    Wt4[i] = __float2bfloat16(Wc[(co * C_ + ci) * 27 + tap]);
  } else if (i < 114688) {                            // Wq (scaled)
    const int i2 = i - 110592;
    const int nf = (i2 >> 10) & 3;
    const int kk = (i2 >> 9) & 1;
    const int l  = (i2 >> 3) & 63;
    const int j  = i2 & 7;
    const int co = nf * 16 + (l & 15);
    const int ci = kk * 32 + ((l >> 4) << 3) + j;
    Wqb[i2] = __float2bfloat16(Wq[co * C_ + ci] * 0.3535533905932738f);
  } else if (i < 118784) {                            // Wo
    const int i3 = i - 114688;
    const int nf = (i3 >> 10) & 3;
    const int kk = (i3 >> 9) & 1;
    const int l  = (i3 >> 3) & 63;
    const int j  = i3 & 7;
    const int co = nf * 16 + (l & 15);
    const int ci = kk * 32 + ((l >> 4) << 3) + j;
    Wob[i3] = __float2bfloat16(Wo[co * C_ + ci]);
  } else if (i < 135168) {                            // Wk / Wv B-frags
    const int i4 = (i - 118784) & 8191;
    const bool is_v = (i - 118784) >= 8192;
    const int ch = i4 >> 12;
    const int kk = (i4 >> 9) & 7;
    const int l  = (i4 >> 3) & 63;
    const int j  = i4 & 7;
    const int c  = ch * 32 + (l & 31);
    const int e  = kk * 16 + ((l >> 5) << 3) + j;
    const float v = (is_v ? Wv : Wk)[c * EMB_ + e];
    (is_v ? Wvb : Wkb)[i4] = __float2bfloat16(v);
  }
}

// ---------------------------------------------------------------------------
// Kernel 1: K/V projections via mfma_32x32x16 (R8 lesson: old 8-block scalar
// version was the TOP kernel at 63 us - latency-bound, 1e6 bank conflicts).
// One block per batch; wave w = (kv = w>>1, ah = w&1). mol staged in PADDED
// LDS [64][132] (stride 132 breaks the stride-128 same-bank column pattern).
// ---------------------------------------------------------------------------
__global__ __launch_bounds__(256) void kv_kernel(
    const float* __restrict__ mol,
    const __hip_bfloat16* __restrict__ Wkb, const float* __restrict__ bk,
    const __hip_bfloat16* __restrict__ Wvb, const float* __restrict__ bv,
    float* __restrict__ kout, float* __restrict__ vout) {
  __shared__ float smol[NATOM][132];   // 33.8 KB padded

  const int b    = blockIdx.x;
  const int tid  = threadIdx.x;
  const int lane = tid & 63;
  const int w    = tid >> 6;
  const int kv   = w >> 1;
  const int ah   = w & 1;

  // stage mol[b] (8192 f32) coalesced, 8 f32x4 per thread
  for (int i = tid; i < 2048; i += 256) {
    const int a = i >> 4, cb = (i & 15) * 8;           // 16 x f32x8 per row
    const f32x4 v0 = *(const f32x4*)&mol[(size_t)(b * NATOM + a) * EMB_ + cb];
    const f32x4 v1 = *(const f32x4*)&mol[(size_t)(b * NATOM + a) * EMB_ + cb + 4];
    *(f32x4*)&smol[a][cb]     = v0;
    *(f32x4*)&smol[a][cb + 4] = v1;
  }
  __syncthreads();

  const __hip_bfloat16* Wb   = kv ? Wvb : Wkb;
  const float*          bias = kv ? bv : bk;
  float*                out  = kv ? vout : kout;

  f32x16 acc[2];
  #pragma unroll
  for (int ch = 0; ch < 2; ++ch)
    #pragma unroll
    for (int r = 0; r < 16; ++r) acc[ch][r] = 0.f;

  const int a  = ah * 32 + (lane & 31);
  #pragma unroll
  for (int kk = 0; kk < 8; ++kk) {
    const int e0 = kk * 16 + ((lane >> 5) << 3);
    ushort8 au;
    #pragma unroll
    for (int j = 0; j < 8; ++j) {
      __hip_bfloat16 hb = __float2bfloat16(smol[a][e0 + j]);
      au[j] = *(unsigned short*)&hb;
    }
    const bf16x8 af = __builtin_bit_cast(bf16x8, au);
    #pragma unroll
    for (int ch = 0; ch < 2; ++ch) {
      const bf16x8 bf = *(const bf16x8*)(Wb + (((ch * 8 + kk) << 6) + lane) * 8);
      acc[ch] = __builtin_amdgcn_mfma_f32_32x32x16_bf16(af, bf, acc[ch], 0, 0, 0);
    }
  }

  // store: contiguous 128B runs per (reg, lane-half)
  #pragma unroll
  for (int ch = 0; ch < 2; ++ch) {
    const int c = ch * 32 + (lane & 31);
    const float bb = bias[c];
    #pragma unroll
    for (int r = 0; r < 16; ++r) {
      const int ar = ah * 32 + (r & 3) + 8 * (r >> 2) + 4 * (lane >> 5);
      out[(size_t)(b * NATOM + ar) * C_ + c] = acc[ch][r] + bb;
    }
  }
}

// ---------------------------------------------------------------------------
// Kernel 2: fused Q-proj(MFMA) + ragged attention(VALU) + O-proj(MFMA) + ReLU.
// (unchanged from R8: VGPR<=64 class, ragged 8-atom chunks w/ early exit)
// ---------------------------------------------------------------------------
__global__ __launch_bounds__(512, 8) void attn_kernel(
    const float* __restrict__ x,
    const float* __restrict__ kbuf, const float* __restrict__ vbuf,
    const int* __restrict__ batch_nodes,
    const __hip_bfloat16* __restrict__ Wqb, const float* __restrict__ bq,
    const __hip_bfloat16* __restrict__ Wob, const float* __restrict__ bo,
    __hip_bfloat16* __restrict__ omid) {
  __shared__ float sk[NATOM * C_];   // 16 KB; becomes os after attention
  __shared__ float sv[NATOM * C_];   // 16 KB
  __shared__ float xq[64 * C_];      // 16 KB: x[c][vox] -> Q[vox][c] -> osb

  const int b    = blockIdx.y;
  const int m0   = blockIdx.x * 64;
  const int tid  = threadIdx.x;
  const int vox  = tid & 63;
  const int lane = tid & 63;
  const int w    = __builtin_amdgcn_readfirstlane(tid >> 6);   // 0..7
  const int quad = lane >> 4;
  const int l15  = lane & 15;
  const int vq   = w & 3;            // vox block for projections
  const int cq   = w >> 2;           // co half for projections

  // ---- stage x tile [c][vox] (16 KB) via global_load_lds ----
  #pragma unroll
  for (int j = 0; j < 2; ++j) {
    const int cidx = w * 2 + j;                  // 0..15
    const int c  = cidx * 4 + (lane >> 4);
    const int v4 = (lane & 15) * 4;
    const float* gsrc = x + (size_t)(b * C_ + c) * MVOX + m0 + v4;
    __builtin_amdgcn_global_load_lds((gas_u32*)gsrc,
                                     (las_u32*)&xq[cidx * 256], 16, 0, 0);
  }
  for (int i = tid; i < NATOM * C_; i += 512) {
    sk[i] = kbuf[b * NATOM * C_ + i];
    sv[i] = vbuf[b * NATOM * C_ + i];
  }
  __syncthreads();

  // ---- Q projection via MFMA: D[vox][co], wave = 16 vox x 32 co ----
  f32x4 qacc[2];
  {
    bf16x8 af[2];
    #pragma unroll
    for (int kk = 0; kk < 2; ++kk) {
      ushort8 au;
      #pragma unroll
      for (int j = 0; j < 8; ++j) {
        const int ci = kk * 32 + quad * 8 + j;
        __hip_bfloat16 hb = __float2bfloat16(xq[ci * 64 + vq * 16 + l15]);
        au[j] = *(unsigned short*)&hb;
      }
      af[kk] = __builtin_bit_cast(bf16x8, au);
    }
    #pragma unroll
    for (int nf2 = 0; nf2 < 2; ++nf2) {
      const int nf = cq * 2 + nf2;
      const float bqv = bq[nf * 16 + l15] * 0.3535533905932738f;
      qacc[nf2] = {bqv, bqv, bqv, bqv};
      #pragma unroll
      for (int kk = 0; kk < 2; ++kk) {
        const bf16x8 bf = *(const bf16x8*)(Wqb + (((nf * 2 + kk) << 6) + lane) * 8);
        qacc[nf2] = __builtin_amdgcn_mfma_f32_16x16x32_bf16(af[kk], bf, qacc[nf2], 0, 0, 0);
      }
    }
  }
  __syncthreads();   // all xq (x-phase) reads done

  // write Q to xq[vox][c] with 16B-chunk swizzle (c4 ^ (vox&15))
  #pragma unroll
  for (int nf2 = 0; nf2 < 2; ++nf2) {
    const int co = (cq * 2 + nf2) * 16 + l15;
    const int c4 = co >> 2, ce = co & 3;
    #pragma unroll
    for (int r = 0; r < 4; ++r) {
      const int vr = vq * 16 + quad * 4 + r;
      xq[vr * 64 + ((c4 ^ (vr & 15)) << 2) + ce] = qacc[nf2][r];
    }
  }
  __syncthreads();

  // ---- ragged attention (VALU), thread = (vox, head w), chunks of 8 ----
  const int h = w;
  float qa[8];
  {
    const f32x4 q0 = *(const f32x4*)&xq[vox * 64 + (((h * 2)     ^ (vox & 15)) << 2)];
    const f32x4 q1 = *(const f32x4*)&xq[vox * 64 + (((h * 2 + 1) ^ (vox & 15)) << 2)];
    qa[0]=q0.x; qa[1]=q0.y; qa[2]=q0.z; qa[3]=q0.w;
    qa[4]=q1.x; qa[5]=q1.y; qa[6]=q1.z; qa[7]=q1.w;
  }
  const int nv    = batch_nodes[b];   // uniform, 1..64
  const int nfull = nv >> 3;
  const int nrem  = nv & 7;
  float mrun = -1e30f, lsum = 0.f;
  float acc[8];
  #pragma unroll
  for (int d = 0; d < 8; ++d) acc[d] = 0.f;

  #pragma unroll 1
  for (int ch = 0; ch < nfull; ++ch) {      // full 8-atom chunks, unmasked
    float l[8];
    float cmax = -1e30f;
    #pragma unroll
    for (int a = 0; a < 8; ++a) {
      const int atom = ch * 8 + a;
      const f32x4 k0 = *(const f32x4*)&sk[atom * C_ + h * 8];
      const f32x4 k1 = *(const f32x4*)&sk[atom * C_ + h * 8 + 4];
      const float lg = qa[0]*k0.x + qa[1]*k0.y + qa[2]*k0.z + qa[3]*k0.w
                     + qa[4]*k1.x + qa[5]*k1.y + qa[6]*k1.z + qa[7]*k1.w;
      l[a] = lg;
      cmax = fmaxf(cmax, lg);
    }
    const float mnew = fmaxf(mrun, cmax);
    const float corr = __expf(mrun - mnew);
    lsum *= corr;
    #pragma unroll
    for (int d = 0; d < 8; ++d) acc[d] *= corr;
    #pragma unroll
    for (int a = 0; a < 8; ++a) {
      const int atom = ch * 8 + a;
      const float p = __expf(l[a] - mnew);
      lsum += p;
      const f32x4 v0 = *(const f32x4*)&sv[atom * C_ + h * 8];
      const f32x4 v1 = *(const f32x4*)&sv[atom * C_ + h * 8 + 4];
      acc[0] += p * v0.x;  acc[1] += p * v0.y;
      acc[2] += p * v0.z;  acc[3] += p * v0.w;
      acc[4] += p * v1.x;  acc[5] += p * v1.y;
      acc[6] += p * v1.z;  acc[7] += p * v1.w;
    }
    mrun = mnew;
  }
  if (nrem) {                               // masked tail chunk
    float l[8];
    float cmax = -1e30f;
    #pragma unroll
    for (int a = 0; a < 8; ++a) {
      const int atom = nfull * 8 + a;
      const f32x4 k0 = *(const f32x4*)&sk[atom * C_ + h * 8];
      const f32x4 k1 = *(const f32x4*)&sk[atom * C_ + h * 8 + 4];
      float lg = qa[0]*k0.x + qa[1]*k0.y + qa[2]*k0.z + qa[3]*k0.w
               + qa[4]*k1.x + qa[5]*k1.y + qa[6]*k1.z + qa[7]*k1.w;
      lg = (a < nrem) ? lg : -1e30f;
      l[a] = lg;
      cmax = fmaxf(cmax, lg);
    }
    const float mnew = fmaxf(mrun, cmax);
    const float corr = __expf(mrun - mnew);
    lsum *= corr;
    #pragma unroll
    for (int d = 0; d < 8; ++d) acc[d] *= corr;
    #pragma unroll
    for (int a = 0; a < 8; ++a) {
      const int atom = nfull * 8 + a;
      const float p = __expf(l[a] - mnew);   // exact 0 for masked atoms
      lsum += p;
      const f32x4 v0 = *(const f32x4*)&sv[atom * C_ + h * 8];
      const f32x4 v1 = *(const f32x4*)&sv[atom * C_ + h * 8 + 4];
      acc[0] += p * v0.x;  acc[1] += p * v0.y;
      acc[2] += p * v0.z;  acc[3] += p * v0.w;
      acc[4] += p * v1.x;  acc[5] += p * v1.y;
      acc[6] += p * v1.z;  acc[7] += p * v1.w;
    }
  }
  const float inv = 1.f / lsum;
  __syncthreads();   // all sk/sv reads done -> sk becomes os

  // write attn out to os (=sk) [vox][c] swizzled
  float* os = sk;
  #pragma unroll
  for (int i = 0; i < 2; ++i) {
    const int c4 = h * 2 + i;
    f32x4 val;
    val.x = acc[i * 4 + 0] * inv; val.y = acc[i * 4 + 1] * inv;
    val.z = acc[i * 4 + 2] * inv; val.w = acc[i * 4 + 3] * inv;
    *(f32x4*)&os[vox * 64 + ((c4 ^ (vox & 15)) << 2)] = val;
  }
  __syncthreads();

  // ---- O projection via MFMA + ReLU -> bf16 exchange in xq ----
  {
    bf16x8 af[2];
    #pragma unroll
    for (int kk = 0; kk < 2; ++kk) {
      ushort8 au;
      #pragma unroll
      for (int j = 0; j < 8; ++j) {
        const int ci = kk * 32 + quad * 8 + j;
        const int c4 = ci >> 2;
        const float f = os[(vq * 16 + l15) * 64 + ((c4 ^ l15) << 2) + (ci & 3)];
        __hip_bfloat16 hb = __float2bfloat16(f);
        au[j] = *(unsigned short*)&hb;
      }
      af[kk] = __builtin_bit_cast(bf16x8, au);
    }
    f32x4 oacc[2];
    #pragma unroll
    for (int nf2 = 0; nf2 < 2; ++nf2) {
      const int nf = cq * 2 + nf2;
      const float bov = bo[nf * 16 + l15];
      oacc[nf2] = {bov, bov, bov, bov};
      #pragma unroll
      for (int kk = 0; kk < 2; ++kk) {
        const bf16x8 bf = *(const bf16x8*)(Wob + (((nf * 2 + kk) << 6) + lane) * 8);
        oacc[nf2] = __builtin_amdgcn_mfma_f32_16x16x32_bf16(af[kk], bf, oacc[nf2], 0, 0, 0);
      }
    }
    // relu + pack bf16 into xq alias at chunk' = chunk ^ (vox&7)
    unsigned short* osb = (unsigned short*)xq;
    #pragma unroll
    for (int nf2 = 0; nf2 < 2; ++nf2) {
      const int co = (cq * 2 + nf2) * 16 + l15;
      #pragma unroll
      for (int r = 0; r < 4; ++r) {
        const int vr = vq * 16 + quad * 4 + r;
        __hip_bfloat16 hb = __float2bfloat16(fmaxf(oacc[nf2][r], 0.f));
        osb[vr * 64 + (((co >> 3) ^ (vr & 7)) << 3) + (co & 7)] = *(unsigned short*)&hb;
      }
    }
  }
  __syncthreads();

  // ---- coalesced store: xq alias already holds conv's swizzled layout ----
  *(ushort8*)(omid + (size_t)(b * MVOX + m0) * C_ + tid * 8) =
      *(const ushort8*)&((unsigned short*)xq)[tid * 8];
}

// ---------------------------------------------------------------------------
// Kernel 3: conv3d 3x3x3 circular, implicit-GEMM mfma_f32_32x32x16_bf16.
// (unchanged from R8: tap-pipelined B-frags, 3-deep weight register ring)
// ---------------------------------------------------------------------------
#define LOADB(dst, DX, DY, DZ)                                              \
  {                                                                         \
    const int zp_ = ((lane & 31) + (DZ) + 31) & 31;                         \
    const int sw_ = zp_ & 7;                                                \
    _Pragma("unroll")                                                       \
    for (int ks_ = 0; ks_ < 4; ++ks_) {                                     \
      const int phys_ = (ks_ * 2 + (lane >> 5)) ^ sw_;                      \
      _Pragma("unroll")                                                     \
      for (int i_ = 0; i_ < 2; ++i_) {                                      \
        const int hl_ = (lp + (DX)) * 4 + (i_ + (DY));                      \
        (dst)[i_ * 4 + ks_] =                                               \
            *(const bf16x8*)&halo[((hl_ * 32 + zp_) * 8 + phys_) * 8];      \
      }                                                                     \
    }                                                                       \
  }

#define LOADW(T2)                                                           \
  _Pragma("unroll")                                                         \
  for (int ks_ = 0; ks_ < 4; ++ks_)                                         \
    wf[(T2) % 3][ks_] =                                                     \
        *(const bf16x8*)(Wt4 + ((((T2) * 2 + coh) * 4 + ks_) << 9) + lane * 8);

#define DOMFMA(src, T)                                                      \
  _Pragma("unroll")                                                         \
  for (int ks_ = 0; ks_ < 4; ++ks_)                                         \
    _Pragma("unroll")                                                       \
    for (int i_ = 0; i_ < 2; ++i_)                                          \
      acc[i_] = __builtin_amdgcn_mfma_f32_32x32x16_bf16(                    \
          wf[(T) % 3][ks_], (src)[i_ * 4 + ks_], acc[i_], 0, 0, 0);

__global__ __launch_bounds__(256, 2) void conv_kernel(
    const __hip_bfloat16* __restrict__ omid,
    const __hip_bfloat16* __restrict__ Wt4,
    const float* __restrict__ bc,
    const float* __restrict__ xin,
    float* __restrict__ out) {
  __shared__ __hip_bfloat16 halo[512 * 64];   // 64 KB

  const int b    = blockIdx.y;
  const int x0   = (blockIdx.x >> 4) * 2;
  const int y0   = (blockIdx.x & 15) * 2;
  const int tid  = threadIdx.x;
  const int lane = tid & 63;
  const int w    = tid >> 6;
  const int coh  = w & 1;
  const int lp   = w >> 1;

  // --- halo staging: 64 chunks x 1KB via global_load_lds ---
  {
    const __hip_bfloat16* src = omid + (size_t)b * MVOX * C_;
    #pragma unroll
    for (int n = 0; n < 16; ++n) {
      const int chunk = w * 16 + n;
      const int li = chunk >> 2;
      const int zb = (chunk & 3) * 8;
      const int gx = (x0 - 1 + (li >> 2)) & 31;
      const int gy = (y0 - 1 + (li & 3)) & 31;
      const __hip_bfloat16* gsrc = src + (size_t)(gx * 1024 + gy * 32 + zb) * C_ + lane * 8;
      __builtin_amdgcn_global_load_lds((gas_u32*)gsrc,
                                       (las_u32*)&halo[chunk * 512], 16, 0, 0);
    }
  }

  // --- weight register ring: prologue loads taps 0,1 ---
  bf16x8 wf[3][4];
  LOADW(0);
  LOADW(1);
  __syncthreads();   // halo staged (drains vmcnt)

  f32x16 acc[2];
  #pragma unroll
  for (int i = 0; i < 2; ++i)
    #pragma unroll
    for (int r = 0; r < 16; ++r) acc[i][r] = 0.f;

  bf16x8 bA[8], bB[8];
  LOADB(bA, 0, 0, 0);   // tap 0

  #pragma unroll
  for (int t = 0; t < 27; ++t) {
    const int dxn = (t + 1) / 9, dyn = ((t + 1) / 3) % 3, dzn = (t + 1) % 3;
    if ((t & 1) == 0) {
      if (t < 26) LOADB(bB, dxn, dyn, dzn);
      if (t < 25) LOADW(t + 2);
      DOMFMA(bA, t);
    } else {
      if (t < 26) LOADB(bA, dxn, dyn, dzn);
      if (t < 25) LOADW(t + 2);
      DOMFMA(bB, t);
    }
  }

  // --- epilogue: relu(acc+bias) + residual ---
  const int z = lane & 31;
  #pragma unroll
  for (int i = 0; i < 2; ++i) {
    const int gx = x0 + lp, gy = y0 + i;
    #pragma unroll
    for (int r = 0; r < 16; ++r) {
      const int co = coh * 32 + (r & 3) + 8 * (r >> 2) + 4 * (lane >> 5);
      const size_t idx = ((size_t)(b * C_ + co)) * MVOX + gx * 1024 + gy * 32 + z;
      out[idx] = fmaxf(acc[i][r] + bc[co], 0.f) + xin[idx];
    }
  }
}

// ---------------------------------------------------------------------------
extern "C" void kernel_launch(void* const* d_in, const int* in_sizes, int n_in,
                              void* d_out, int out_size, void* d_ws, size_t ws_size,
                              hipStream_t stream) {
  const float* x   = (const float*)d_in[0];
  const float* mol = (const float*)d_in[1];
  const int*   bn  = (const int*)  d_in[2];
  const float* Wq  = (const float*)d_in[3];
  const float* bq  = (const float*)d_in[4];
  const float* Wk  = (const float*)d_in[5];
  const float* bk  = (const float*)d_in[6];
  const float* Wv  = (const float*)d_in[7];
  const float* bv  = (const float*)d_in[8];
  const float* Wo  = (const float*)d_in[9];
  const float* bo  = (const float*)d_in[10];
  const float* Wc  = (const float*)d_in[11];
  const float* bc  = (const float*)d_in[12];
  float* out = (float*)d_out;

  char* ws = (char*)d_ws;
  __hip_bfloat16* omid = (__hip_bfloat16*)ws;                     // 16,777,216 B
  float* kbuf = (float*)(ws + 16777216);                          // 65,536 B
  float* vbuf = kbuf + B_ * NATOM * C_;                           // 65,536 B
  __hip_bfloat16* Wt4 = (__hip_bfloat16*)(ws + 16908288);         // 221,184 B
  __hip_bfloat16* Wqb = (__hip_bfloat16*)(ws + 17129472);         // 8,192 B
  __hip_bfloat16* Wob = (__hip_bfloat16*)(ws + 17137664);         // 8,192 B
  __hip_bfloat16* Wkb = (__hip_bfloat16*)(ws + 17145856);         // 16,384 B
  __hip_bfloat16* Wvb = (__hip_bfloat16*)(ws + 17162240);         // 16,384 B

  wprep_kernel<<<dim3(528), 256, 0, stream>>>(Wc, Wq, Wo, Wk, Wv,
                                              Wt4, Wqb, Wob, Wkb, Wvb);
  kv_kernel<<<dim3(B_), 256, 0, stream>>>(mol, Wkb, bk, Wvb, bv, kbuf, vbuf);
  attn_kernel<<<dim3(MVOX / 64, B_), 512, 0, stream>>>(x, kbuf, vbuf, bn, Wqb, bq, Wob, bo, omid);
  conv_kernel<<<dim3(256, B_), 256, 0, stream>>>(omid, Wt4, bc, x, out);
}

// Round 10
// 88.686 us; speedup vs baseline: 2.5280x; 1.0790x over previous
//
#include <hip/hip_runtime.h>
#include <hip/hip_bf16.h>

#define B_    4
#define C_    64
#define MVOX  32768      // 32*32*32
#define NATOM 64
#define EMB_  128

typedef __attribute__((ext_vector_type(8)))  __bf16 bf16x8;
typedef __attribute__((ext_vector_type(4)))  float  f32x4;
typedef __attribute__((ext_vector_type(16))) float  f32x16;
typedef __attribute__((ext_vector_type(8)))  unsigned short ushort8;

typedef __attribute__((address_space(1))) const unsigned int gas_u32;
typedef __attribute__((address_space(3))) unsigned int las_u32;

static __device__ __forceinline__ unsigned short bf16u(float f) {
  __hip_bfloat16 h = __float2bfloat16(f);
  return *(unsigned short*)&h;
}

// ---------------------------------------------------------------------------
// Kernel 0: weight prep (unchanged from R9).
// ---------------------------------------------------------------------------
__global__ __launch_bounds__(256) void wprep_kernel(
    const float* __restrict__ Wc, const float* __restrict__ Wq,
    const float* __restrict__ Wo, const float* __restrict__ Wk,
    const float* __restrict__ Wv,
    __hip_bfloat16* __restrict__ Wt4, __hip_bfloat16* __restrict__ Wqb,
    __hip_bfloat16* __restrict__ Wob, __hip_bfloat16* __restrict__ Wkb,
    __hip_bfloat16* __restrict__ Wvb) {
  const int i = blockIdx.x * 256 + threadIdx.x;
  if (i < 110592) {                                   // conv weights
    const int tap = i >> 12;
    const int coh = (i >> 11) & 1;
    const int ks  = (i >> 9) & 3;
    const int l   = (i >> 3) & 63;
    const int j   = i & 7;
    const int co  = coh * 32 + (l & 31);
    const int ci  = ks * 16 + ((l >> 5) << 3) + j;
    Wt4[i] = __float2bfloat16(Wc[(co * C_ + ci) * 27 + tap]);
  } else if (i < 114688) {                            // Wq (scaled)
    const int i2 = i - 110592;
    const int nf = (i2 >> 10) & 3;
    const int kk = (i2 >> 9) & 1;
    const int l  = (i2 >> 3) & 63;
    const int j  = i2 & 7;
    const int co = nf * 16 + (l & 15);
    const int ci = kk * 32 + ((l >> 4) << 3) + j;
    Wqb[i2] = __float2bfloat16(Wq[co * C_ + ci] * 0.3535533905932738f);
  } else if (i < 118784) {                            // Wo
    const int i3 = i - 114688;
    const int nf = (i3 >> 10) & 3;
    const int kk = (i3 >> 9) & 1;
    const int l  = (i3 >> 3) & 63;
    const int j  = i3 & 7;
    const int co = nf * 16 + (l & 15);
    const int ci = kk * 32 + ((l >> 4) << 3) + j;
    Wob[i3] = __float2bfloat16(Wo[co * C_ + ci]);
  } else if (i < 135168) {                            // Wk / Wv B-frags
    const int i4 = (i - 118784) & 8191;
    const bool is_v = (i - 118784) >= 8192;
    const int ch = i4 >> 12;
    const int kk = (i4 >> 9) & 7;
    const int l  = (i4 >> 3) & 63;
    const int j  = i4 & 7;
    const int c  = ch * 32 + (l & 31);
    const int e  = kk * 16 + ((l >> 5) << 3) + j;
    const float v = (is_v ? Wv : Wk)[c * EMB_ + e];
    (is_v ? Wvb : Wkb)[i4] = __float2bfloat16(v);
  }
}

// ---------------------------------------------------------------------------
// Kernel 1: K/V projections via mfma_32x32x16 (unchanged from R9).
// ---------------------------------------------------------------------------
__global__ __launch_bounds__(256) void kv_kernel(
    const float* __restrict__ mol,
    const __hip_bfloat16* __restrict__ Wkb, const float* __restrict__ bk,
    const __hip_bfloat16* __restrict__ Wvb, const float* __restrict__ bv,
    float* __restrict__ kout, float* __restrict__ vout) {
  __shared__ float smol[NATOM][132];   // padded

  const int b    = blockIdx.x;
  const int tid  = threadIdx.x;
  const int lane = tid & 63;
  const int w    = tid >> 6;
  const int kv   = w >> 1;
  const int ah   = w & 1;

  for (int i = tid; i < 2048; i += 256) {
    const int a = i >> 4, cb = (i & 15) * 8;
    const f32x4 v0 = *(const f32x4*)&mol[(size_t)(b * NATOM + a) * EMB_ + cb];
    const f32x4 v1 = *(const f32x4*)&mol[(size_t)(b * NATOM + a) * EMB_ + cb + 4];
    *(f32x4*)&smol[a][cb]     = v0;
    *(f32x4*)&smol[a][cb + 4] = v1;
  }
  __syncthreads();

  const __hip_bfloat16* Wb   = kv ? Wvb : Wkb;
  const float*          bias = kv ? bv : bk;
  float*                out  = kv ? vout : kout;

  f32x16 acc[2];
  #pragma unroll
  for (int ch = 0; ch < 2; ++ch)
    #pragma unroll
    for (int r = 0; r < 16; ++r) acc[ch][r] = 0.f;

  const int a  = ah * 32 + (lane & 31);
  #pragma unroll
  for (int kk = 0; kk < 8; ++kk) {
    const int e0 = kk * 16 + ((lane >> 5) << 3);
    ushort8 au;
    #pragma unroll
    for (int j = 0; j < 8; ++j) au[j] = bf16u(smol[a][e0 + j]);
    const bf16x8 af = __builtin_bit_cast(bf16x8, au);
    #pragma unroll
    for (int ch = 0; ch < 2; ++ch) {
      const bf16x8 bf = *(const bf16x8*)(Wb + (((ch * 8 + kk) << 6) + lane) * 8);
      acc[ch] = __builtin_amdgcn_mfma_f32_32x32x16_bf16(af, bf, acc[ch], 0, 0, 0);
    }
  }

  #pragma unroll
  for (int ch = 0; ch < 2; ++ch) {
    const int c = ch * 32 + (lane & 31);
    const float bb = bias[c];
    #pragma unroll
    for (int r = 0; r < 16; ++r) {
      const int ar = ah * 32 + (r & 3) + 8 * (r >> 2) + 4 * (lane >> 5);
      out[(size_t)(b * NATOM + ar) * C_ + c] = acc[ch][r] + bb;
    }
  }
}

// ---------------------------------------------------------------------------
// Kernel 2: fully-MFMA fused attention.
// 512 thr = 8 waves, wave = head h. Swapped QK^T (S^T = mfma(K, Q)) with
// 16x16x32 shapes: D-layout of S^T (col=vox=l&15, row=atom=(l>>4)*4+reg) IS
// the A-frag layout of PV (row=l&15, k=(l>>4)*8+j) -> lane-local softmax
// (in-lane 16 atoms + shfl_xor 16/32 cross-group), normalize P in-lane,
// cvt->bf16, straight into PV MFMA. d=8 zero-padded to K=32 (A zeroed for
// lane-groups>=1). Ragged mask: atom>=nv -> -1e30 -> exp=0 (branch-free).
// sk/sv stored 16B-chunk-XOR-swizzled (conflict-free K A-frag b128 reads).
// ---------------------------------------------------------------------------
__global__ __launch_bounds__(512, 4) void attn_kernel(
    const float* __restrict__ x,
    const float* __restrict__ kbuf, const float* __restrict__ vbuf,
    const int* __restrict__ batch_nodes,
    const __hip_bfloat16* __restrict__ Wqb, const float* __restrict__ bq,
    const __hip_bfloat16* __restrict__ Wob, const float* __restrict__ bo,
    __hip_bfloat16* __restrict__ omid) {
  __shared__ float sk[NATOM * C_];   // K swizzled; becomes os after attention
  __shared__ float sv[NATOM * C_];   // V swizzled
  __shared__ float xq[64 * C_];      // x[c][vox] -> Q[vox][c] swz -> osb

  const int b    = blockIdx.y;
  const int m0   = blockIdx.x * 64;
  const int tid  = threadIdx.x;
  const int lane = tid & 63;
  const int w    = __builtin_amdgcn_readfirstlane(tid >> 6);   // 0..7
  const int h    = w;
  const int quad = lane >> 4;
  const int l15  = lane & 15;
  const int vq   = w & 3;            // vox block for projections
  const int cq   = w >> 2;           // co half for projections

  // ---- stage x tile [c][vox] via global_load_lds ----
  #pragma unroll
  for (int j = 0; j < 2; ++j) {
    const int cidx = w * 2 + j;
    const int c  = cidx * 4 + (lane >> 4);
    const int v4 = (lane & 15) * 4;
    const float* gsrc = x + (size_t)(b * C_ + c) * MVOX + m0 + v4;
    __builtin_amdgcn_global_load_lds((gas_u32*)gsrc,
                                     (las_u32*)&xq[cidx * 256], 16, 0, 0);
  }
  // stage K/V with 16B-chunk swizzle: [atom][(c4 ^ (atom&15))*4 + c&3]
  for (int i = tid; i < NATOM * C_; i += 512) {
    const int at = i >> 6, c = i & 63;
    const int ad = (at << 6) + ((((c >> 2) ^ (at & 15)) << 2)) + (c & 3);
    sk[ad] = kbuf[b * NATOM * C_ + i];
    sv[ad] = vbuf[b * NATOM * C_ + i];
  }
  __syncthreads();

  // ---- Q projection via MFMA: D[vox][co], wave = 16 vox x 32 co ----
  f32x4 qacc[2];
  {
    bf16x8 af[2];
    #pragma unroll
    for (int kk = 0; kk < 2; ++kk) {
      ushort8 au;
      #pragma unroll
      for (int j = 0; j < 8; ++j)
        au[j] = bf16u(xq[(kk * 32 + quad * 8 + j) * 64 + vq * 16 + l15]);
      af[kk] = __builtin_bit_cast(bf16x8, au);
    }
    #pragma unroll
    for (int nf2 = 0; nf2 < 2; ++nf2) {
      const int nf = cq * 2 + nf2;
      const float bqv = bq[nf * 16 + l15] * 0.3535533905932738f;
      qacc[nf2] = {bqv, bqv, bqv, bqv};
      #pragma unroll
      for (int kk = 0; kk < 2; ++kk) {
        const bf16x8 bf = *(const bf16x8*)(Wqb + (((nf * 2 + kk) << 6) + lane) * 8);
        qacc[nf2] = __builtin_amdgcn_mfma_f32_16x16x32_bf16(af[kk], bf, qacc[nf2], 0, 0, 0);
      }
    }
  }
  __syncthreads();   // all xq (x-phase) reads done

  // write Q to xq[vox][c] with 16B-chunk swizzle (c4 ^ (vox&15))
  #pragma unroll
  for (int nf2 = 0; nf2 < 2; ++nf2) {
    const int co = (cq * 2 + nf2) * 16 + l15;
    const int c4 = co >> 2, ce = co & 3;
    #pragma unroll
    for (int r = 0; r < 4; ++r) {
      const int vr = vq * 16 + quad * 4 + r;
      xq[vr * 64 + ((c4 ^ (vr & 15)) << 2) + ce] = qacc[nf2][r];
    }
  }
  __syncthreads();

  // ================== MFMA attention core ==================
  const int nv = batch_nodes[b];

  // K A-frags: af[a]: row=atom a*16+l15, k-slot (quad,j) = d=quad*8+j
  // (real only quad==0; others zeroed so Q-side garbage is annihilated)
  bf16x8 kf[4];
  #pragma unroll
  for (int a = 0; a < 4; ++a) {
    const int arow = a * 16 + l15;
    const f32x4 k0 = *(const f32x4*)&sk[arow * 64 + (((2 * h)     ^ l15) << 2)];
    const f32x4 k1 = *(const f32x4*)&sk[arow * 64 + (((2 * h + 1) ^ l15) << 2)];
    ushort8 au;
    #pragma unroll
    for (int j = 0; j < 4; ++j) {
      au[j]     = (quad == 0) ? bf16u(k0[j]) : (unsigned short)0;
      au[4 + j] = (quad == 0) ? bf16u(k1[j]) : (unsigned short)0;
    }
    kf[a] = __builtin_bit_cast(bf16x8, au);
  }
  // V B-frags: vf[s]: col=l15 (c = h*8 + (l15&7); cols 8-15 duplicate 0-7,
  // discarded), k-slot (quad,j) -> atom = (2s+(j>>2))*16 + quad*4 + (j&3)
  bf16x8 vf[2];
  {
    const int vc  = h * 8 + (l15 & 7);
    const int vc4 = vc >> 2, vce = vc & 3;
    #pragma unroll
    for (int s = 0; s < 2; ++s) {
      ushort8 au;
      #pragma unroll
      for (int j = 0; j < 8; ++j) {
        const int atom = (2 * s + (j >> 2)) * 16 + quad * 4 + (j & 3);
        au[j] = bf16u(sv[(atom << 6) + ((vc4 ^ (atom & 15)) << 2) + vce]);
      }
      vf[s] = __builtin_bit_cast(bf16x8, au);
    }
  }

  f32x4 oacc[4];
  #pragma unroll
  for (int v = 0; v < 4; ++v)
    #pragma unroll
    for (int r = 0; r < 4; ++r) oacc[v][r] = 0.f;

  const f32x4 zero4 = {0.f, 0.f, 0.f, 0.f};
  #pragma unroll
  for (int v = 0; v < 4; ++v) {
    // Q B-frag for vox tile v (garbage in quad>=1 slots; A zeros cover it)
    const int qrow = v * 16 + l15;
    const f32x4 q0 = *(const f32x4*)&xq[qrow * 64 + (((2 * h)     ^ l15) << 2)];
    const f32x4 q1 = *(const f32x4*)&xq[qrow * 64 + (((2 * h + 1) ^ l15) << 2)];
    ushort8 qu;
    #pragma unroll
    for (int j = 0; j < 4; ++j) { qu[j] = bf16u(q0[j]); qu[4 + j] = bf16u(q1[j]); }
    const bf16x8 qf = __builtin_bit_cast(bf16x8, qu);

    // S^T tiles: st[a] = K_a @ Q_v^T   (lane: col=vox, rows=atoms)
    f32x4 st[4];
    #pragma unroll
    for (int a = 0; a < 4; ++a)
      st[a] = __builtin_amdgcn_mfma_f32_16x16x32_bf16(kf[a], qf, zero4, 0, 0, 0);

    // mask + row max (in-lane 16 atoms + cross-group xor 16/32)
    float m = -1e30f;
    #pragma unroll
    for (int a = 0; a < 4; ++a)
      #pragma unroll
      for (int r = 0; r < 4; ++r) {
        const int atom = a * 16 + quad * 4 + r;
        const float val = (atom < nv) ? st[a][r] : -1e30f;
        st[a][r] = val;
        m = fmaxf(m, val);
      }
    m = fmaxf(m, __shfl_xor(m, 16, 64));
    m = fmaxf(m, __shfl_xor(m, 32, 64));
    float ssum = 0.f;
    #pragma unroll
    for (int a = 0; a < 4; ++a)
      #pragma unroll
      for (int r = 0; r < 4; ++r) {
        const float p = __expf(st[a][r] - m);
        st[a][r] = p;
        ssum += p;
      }
    ssum += __shfl_xor(ssum, 16, 64);
    ssum += __shfl_xor(ssum, 32, 64);
    const float inv = 1.f / ssum;

    // P (normalized, bf16) -> PV A-frags; D-layout == A-frag layout
    #pragma unroll
    for (int s = 0; s < 2; ++s) {
      ushort8 pu;
      #pragma unroll
      for (int j = 0; j < 8; ++j)
        pu[j] = bf16u(st[2 * s + (j >> 2)][j & 3] * inv);
      const bf16x8 pa = __builtin_bit_cast(bf16x8, pu);
      oacc[v] = __builtin_amdgcn_mfma_f32_16x16x32_bf16(pa, vf[s], oacc[v], 0, 0, 0);
    }
  }
  __syncthreads();   // all sk/sv reads done -> sk becomes os

  // write O to os (=sk), swizzled [vox][c]; lane cols valid only l15<8
  float* os = sk;
  if (l15 < 8) {
    const int c = h * 8 + l15;
    const int c4 = c >> 2, ce = c & 3;
    #pragma unroll
    for (int v = 0; v < 4; ++v)
      #pragma unroll
      for (int r = 0; r < 4; ++r) {
        const int vxr = v * 16 + quad * 4 + r;
        os[vxr * 64 + ((c4 ^ (vxr & 15)) << 2) + ce] = oacc[v][r];
      }
  }
  __syncthreads();

  // ---- O projection via MFMA + ReLU -> bf16 exchange in xq ----
  {
    bf16x8 af[2];
    #pragma unroll
    for (int kk = 0; kk < 2; ++kk) {
      ushort8 au;
      #pragma unroll
      for (int j = 0; j < 8; ++j) {
        const int ci = kk * 32 + quad * 8 + j;
        const int c4 = ci >> 2;
        au[j] = bf16u(os[(vq * 16 + l15) * 64 + ((c4 ^ l15) << 2) + (ci & 3)]);
      }
      af[kk] = __builtin_bit_cast(bf16x8, au);
    }
    f32x4 oac[2];
    #pragma unroll
    for (int nf2 = 0; nf2 < 2; ++nf2) {
      const int nf = cq * 2 + nf2;
      const float bov = bo[nf * 16 + l15];
      oac[nf2] = {bov, bov, bov, bov};
      #pragma unroll
      for (int kk = 0; kk < 2; ++kk) {
        const bf16x8 bf = *(const bf16x8*)(Wob + (((nf * 2 + kk) << 6) + lane) * 8);
        oac[nf2] = __builtin_amdgcn_mfma_f32_16x16x32_bf16(af[kk], bf, oac[nf2], 0, 0, 0);
      }
    }
    __syncthreads();   // all os reads done before xq alias-overwrite
    unsigned short* osb = (unsigned short*)xq;
    #pragma unroll
    for (int nf2 = 0; nf2 < 2; ++nf2) {
      const int co = (cq * 2 + nf2) * 16 + l15;
      #pragma unroll
      for (int r = 0; r < 4; ++r) {
        const int vr = vq * 16 + quad * 4 + r;
        osb[vr * 64 + (((co >> 3) ^ (vr & 7)) << 3) + (co & 7)] =
            bf16u(fmaxf(oac[nf2][r], 0.f));
      }
    }
  }
  __syncthreads();

  // ---- coalesced store: xq alias already holds conv's swizzled layout ----
  *(ushort8*)(omid + (size_t)(b * MVOX + m0) * C_ + tid * 8) =
      *(const ushort8*)&((unsigned short*)xq)[tid * 8];
}

// ---------------------------------------------------------------------------
// Kernel 3: conv3d 3x3x3 circular (unchanged from R9).
// ---------------------------------------------------------------------------
#define LOADB(dst, DX, DY, DZ)                                              \
  {                                                                         \
    const int zp_ = ((lane & 31) + (DZ) + 31) & 31;                         \
    const int sw_ = zp_ & 7;                                                \
    _Pragma("unroll")                                                       \
    for (int ks_ = 0; ks_ < 4; ++ks_) {                                     \
      const int phys_ = (ks_ * 2 + (lane >> 5)) ^ sw_;                      \
      _Pragma("unroll")                                                     \
      for (int i_ = 0; i_ < 2; ++i_) {                                      \
        const int hl_ = (lp + (DX)) * 4 + (i_ + (DY));                      \
        (dst)[i_ * 4 + ks_] =                                               \
            *(const bf16x8*)&halo[((hl_ * 32 + zp_) * 8 + phys_) * 8];      \
      }                                                                     \
    }                                                                       \
  }

#define LOADW(T2)                                                           \
  _Pragma("unroll")                                                         \
  for (int ks_ = 0; ks_ < 4; ++ks_)                                         \
    wf[(T2) % 3][ks_] =                                                     \
        *(const bf16x8*)(Wt4 + ((((T2) * 2 + coh) * 4 + ks_) << 9) + lane * 8);

#define DOMFMA(src, T)                                                      \
  _Pragma("unroll")                                                         \
  for (int ks_ = 0; ks_ < 4; ++ks_)                                         \
    _Pragma("unroll")                                                       \
    for (int i_ = 0; i_ < 2; ++i_)                                          \
      acc[i_] = __builtin_amdgcn_mfma_f32_32x32x16_bf16(                    \
          wf[(T) % 3][ks_], (src)[i_ * 4 + ks_], acc[i_], 0, 0, 0);

__global__ __launch_bounds__(256, 2) void conv_kernel(
    const __hip_bfloat16* __restrict__ omid,
    const __hip_bfloat16* __restrict__ Wt4,
    const float* __restrict__ bc,
    const float* __restrict__ xin,
    float* __restrict__ out) {
  __shared__ __hip_bfloat16 halo[512 * 64];   // 64 KB

  const int b    = blockIdx.y;
  const int x0   = (blockIdx.x >> 4) * 2;
  const int y0   = (blockIdx.x & 15) * 2;
  const int tid  = threadIdx.x;
  const int lane = tid & 63;
  const int w    = tid >> 6;
  const int coh  = w & 1;
  const int lp   = w >> 1;

  {
    const __hip_bfloat16* src = omid + (size_t)b * MVOX * C_;
    #pragma unroll
    for (int n = 0; n < 16; ++n) {
      const int chunk = w * 16 + n;
      const int li = chunk >> 2;
      const int zb = (chunk & 3) * 8;
      const int gx = (x0 - 1 + (li >> 2)) & 31;
      const int gy = (y0 - 1 + (li & 3)) & 31;
      const __hip_bfloat16* gsrc = src + (size_t)(gx * 1024 + gy * 32 + zb) * C_ + lane * 8;
      __builtin_amdgcn_global_load_lds((gas_u32*)gsrc,
                                       (las_u32*)&halo[chunk * 512], 16, 0, 0);
    }
  }

  bf16x8 wf[3][4];
  LOADW(0);
  LOADW(1);
  __syncthreads();

  f32x16 acc[2];
  #pragma unroll
  for (int i = 0; i < 2; ++i)
    #pragma unroll
    for (int r = 0; r < 16; ++r) acc[i][r] = 0.f;

  bf16x8 bA[8], bB[8];
  LOADB(bA, 0, 0, 0);

  #pragma unroll
  for (int t = 0; t < 27; ++t) {
    const int dxn = (t + 1) / 9, dyn = ((t + 1) / 3) % 3, dzn = (t + 1) % 3;
    if ((t & 1) == 0) {
      if (t < 26) LOADB(bB, dxn, dyn, dzn);
      if (t < 25) LOADW(t + 2);
      DOMFMA(bA, t);
    } else {
      if (t < 26) LOADB(bA, dxn, dyn, dzn);
      if (t < 25) LOADW(t + 2);
      DOMFMA(bB, t);
    }
  }

  const int z = lane & 31;
  #pragma unroll
  for (int i = 0; i < 2; ++i) {
    const int gx = x0 + lp, gy = y0 + i;
    #pragma unroll
    for (int r = 0; r < 16; ++r) {
      const int co = coh * 32 + (r & 3) + 8 * (r >> 2) + 4 * (lane >> 5);
      const size_t idx = ((size_t)(b * C_ + co)) * MVOX + gx * 1024 + gy * 32 + z;
      out[idx] = fmaxf(acc[i][r] + bc[co], 0.f) + xin[idx];
    }
  }
}

// ---------------------------------------------------------------------------
extern "C" void kernel_launch(void* const* d_in, const int* in_sizes, int n_in,
                              void* d_out, int out_size, void* d_ws, size_t ws_size,
                              hipStream_t stream) {
  const float* x   = (const float*)d_in[0];
  const float* mol = (const float*)d_in[1];
  const int*   bn  = (const int*)  d_in[2];
  const float* Wq  = (const float*)d_in[3];
  const float* bq  = (const float*)d_in[4];
  const float* Wk  = (const float*)d_in[5];
  const float* bk  = (const float*)d_in[6];
  const float* Wv  = (const float*)d_in[7];
  const float* bv  = (const float*)d_in[8];
  const float* Wo  = (const float*)d_in[9];
  const float* bo  = (const float*)d_in[10];
  const float* Wc  = (const float*)d_in[11];
  const float* bc  = (const float*)d_in[12];
  float* out = (float*)d_out;

  char* ws = (char*)d_ws;
  __hip_bfloat16* omid = (__hip_bfloat16*)ws;                     // 16,777,216 B
  float* kbuf = (float*)(ws + 16777216);
  float* vbuf = kbuf + B_ * NATOM * C_;
  __hip_bfloat16* Wt4 = (__hip_bfloat16*)(ws + 16908288);
  __hip_bfloat16* Wqb = (__hip_bfloat16*)(ws + 17129472);
  __hip_bfloat16* Wob = (__hip_bfloat16*)(ws + 17137664);
  __hip_bfloat16* Wkb = (__hip_bfloat16*)(ws + 17145856);
  __hip_bfloat16* Wvb = (__hip_bfloat16*)(ws + 17162240);

  wprep_kernel<<<dim3(528), 256, 0, stream>>>(Wc, Wq, Wo, Wk, Wv,
                                              Wt4, Wqb, Wob, Wkb, Wvb);
  kv_kernel<<<dim3(B_), 256, 0, stream>>>(mol, Wkb, bk, Wvb, bv, kbuf, vbuf);
  attn_kernel<<<dim3(MVOX / 64, B_), 512, 0, stream>>>(x, kbuf, vbuf, bn, Wqb, bq, Wob, bo, omid);
  conv_kernel<<<dim3(256, B_), 256, 0, stream>>>(omid, Wt4, bc, x, out);
}

// Round 11
// 83.391 us; speedup vs baseline: 2.6885x; 1.0635x over previous
//
#include <hip/hip_runtime.h>
#include <hip/hip_bf16.h>

#define B_    4
#define C_    64
#define MVOX  32768      // 32*32*32
#define NATOM 64
#define EMB_  128

typedef __attribute__((ext_vector_type(8)))  __bf16 bf16x8;
typedef __attribute__((ext_vector_type(4)))  float  f32x4;
typedef __attribute__((ext_vector_type(16))) float  f32x16;
typedef __attribute__((ext_vector_type(8)))  unsigned short ushort8;

typedef __attribute__((address_space(1))) const unsigned int gas_u32;
typedef __attribute__((address_space(3))) unsigned int las_u32;

static __device__ __forceinline__ unsigned short bf16u(float f) {
  __hip_bfloat16 h = __float2bfloat16(f);
  return *(unsigned short*)&h;
}

// ---------------------------------------------------------------------------
// Kernel 0: weight prep (unchanged from R10).
// ---------------------------------------------------------------------------
__global__ __launch_bounds__(256) void wprep_kernel(
    const float* __restrict__ Wc, const float* __restrict__ Wq,
    const float* __restrict__ Wo, const float* __restrict__ Wk,
    const float* __restrict__ Wv,
    __hip_bfloat16* __restrict__ Wt4, __hip_bfloat16* __restrict__ Wqb,
    __hip_bfloat16* __restrict__ Wob, __hip_bfloat16* __restrict__ Wkb,
    __hip_bfloat16* __restrict__ Wvb) {
  const int i = blockIdx.x * 256 + threadIdx.x;
  if (i < 110592) {                                   // conv weights
    const int tap = i >> 12;
    const int coh = (i >> 11) & 1;
    const int ks  = (i >> 9) & 3;
    const int l   = (i >> 3) & 63;
    const int j   = i & 7;
    const int co  = coh * 32 + (l & 31);
    const int ci  = ks * 16 + ((l >> 5) << 3) + j;
    Wt4[i] = __float2bfloat16(Wc[(co * C_ + ci) * 27 + tap]);
  } else if (i < 114688) {                            // Wq (scaled)
    const int i2 = i - 110592;
    const int nf = (i2 >> 10) & 3;
    const int kk = (i2 >> 9) & 1;
    const int l  = (i2 >> 3) & 63;
    const int j  = i2 & 7;
    const int co = nf * 16 + (l & 15);
    const int ci = kk * 32 + ((l >> 4) << 3) + j;
    Wqb[i2] = __float2bfloat16(Wq[co * C_ + ci] * 0.3535533905932738f);
  } else if (i < 118784) {                            // Wo
    const int i3 = i - 114688;
    const int nf = (i3 >> 10) & 3;
    const int kk = (i3 >> 9) & 1;
    const int l  = (i3 >> 3) & 63;
    const int j  = i3 & 7;
    const int co = nf * 16 + (l & 15);
    const int ci = kk * 32 + ((l >> 4) << 3) + j;
    Wob[i3] = __float2bfloat16(Wo[co * C_ + ci]);
  } else if (i < 135168) {                            // Wk / Wv B-frags
    const int i4 = (i - 118784) & 8191;
    const bool is_v = (i - 118784) >= 8192;
    const int ch = i4 >> 12;
    const int kk = (i4 >> 9) & 7;
    const int l  = (i4 >> 3) & 63;
    const int j  = i4 & 7;
    const int c  = ch * 32 + (l & 31);
    const int e  = kk * 16 + ((l >> 5) << 3) + j;
    const float v = (is_v ? Wv : Wk)[c * EMB_ + e];
    (is_v ? Wvb : Wkb)[i4] = __float2bfloat16(v);
  }
}

// ---------------------------------------------------------------------------
// Kernel 1: K/V projection via MFMA + direct emission of attn's MFMA
// fragment buffers (R10 lesson: attn re-built these per block = the VALU
// bill). kfb[(b*8+h)*4+a][lane]: quad==0 -> K[a*16+l15][h*8..+8], else 0.
// vfb[(b*8+h)*2+s][lane]: au[j] = V[(2s+(j>>2))*16+quad*4+(j&3)][h*8+(l15&7)].
// ---------------------------------------------------------------------------
__global__ __launch_bounds__(256) void kv_kernel(
    const float* __restrict__ mol,
    const __hip_bfloat16* __restrict__ Wkb, const float* __restrict__ bk,
    const __hip_bfloat16* __restrict__ Wvb, const float* __restrict__ bv,
    unsigned short* __restrict__ kfb, unsigned short* __restrict__ vfb) {
  __shared__ float smol[NATOM][132];      // 33.8 KB
  __shared__ float res[2][NATOM][68];     // K/V results [atom][c], 34.8 KB

  const int b    = blockIdx.x;
  const int tid  = threadIdx.x;
  const int lane = tid & 63;
  const int w    = tid >> 6;
  const int kvw  = w >> 1;
  const int ah   = w & 1;

  for (int i = tid; i < 2048; i += 256) {
    const int a = i >> 4, cb = (i & 15) * 8;
    const f32x4 v0 = *(const f32x4*)&mol[(size_t)(b * NATOM + a) * EMB_ + cb];
    const f32x4 v1 = *(const f32x4*)&mol[(size_t)(b * NATOM + a) * EMB_ + cb + 4];
    *(f32x4*)&smol[a][cb]     = v0;
    *(f32x4*)&smol[a][cb + 4] = v1;
  }
  __syncthreads();

  const __hip_bfloat16* Wb   = kvw ? Wvb : Wkb;
  const float*          bias = kvw ? bv : bk;

  f32x16 acc[2];
  #pragma unroll
  for (int ch = 0; ch < 2; ++ch)
    #pragma unroll
    for (int r = 0; r < 16; ++r) acc[ch][r] = 0.f;

  const int a = ah * 32 + (lane & 31);
  #pragma unroll
  for (int kk = 0; kk < 8; ++kk) {
    const int e0 = kk * 16 + ((lane >> 5) << 3);
    ushort8 au;
    #pragma unroll
    for (int j = 0; j < 8; ++j) au[j] = bf16u(smol[a][e0 + j]);
    const bf16x8 af = __builtin_bit_cast(bf16x8, au);
    #pragma unroll
    for (int ch = 0; ch < 2; ++ch) {
      const bf16x8 bf = *(const bf16x8*)(Wb + (((ch * 8 + kk) << 6) + lane) * 8);
      acc[ch] = __builtin_amdgcn_mfma_f32_32x32x16_bf16(af, bf, acc[ch], 0, 0, 0);
    }
  }

  // scatter results (+bias) to LDS [kv][atom][c]
  #pragma unroll
  for (int ch = 0; ch < 2; ++ch) {
    const int c = ch * 32 + (lane & 31);
    const float bb = bias[c];
    #pragma unroll
    for (int r = 0; r < 16; ++r) {
      const int ar = ah * 32 + (r & 3) + 8 * (r >> 2) + 4 * (lane >> 5);
      res[kvw][ar][c] = acc[ch][r] + bb;
    }
  }
  __syncthreads();

  // emit K fragment buffer: 2048 entries (h,a,lane)
  #pragma unroll
  for (int t = 0; t < 8; ++t) {
    const int idx = t * 256 + tid;
    const int h = idx >> 8, aa = (idx >> 6) & 3, ln = idx & 63;
    const int qd = ln >> 4, l15 = ln & 15;
    ushort8 au;
    if (qd == 0) {
      #pragma unroll
      for (int j = 0; j < 8; ++j) au[j] = bf16u(res[0][aa * 16 + l15][h * 8 + j]);
    } else {
      #pragma unroll
      for (int j = 0; j < 8; ++j) au[j] = 0;
    }
    *(ushort8*)(kfb + (size_t)(((b * 8 + h) * 4 + aa) * 64 + ln) * 8) = au;
  }
  // emit V fragment buffer: 1024 entries (h,s,lane)
  #pragma unroll
  for (int t = 0; t < 4; ++t) {
    const int idx = t * 256 + tid;
    const int h = idx >> 7, s = (idx >> 6) & 1, ln = idx & 63;
    const int qd = ln >> 4, l15 = ln & 15;
    ushort8 au;
    #pragma unroll
    for (int j = 0; j < 8; ++j) {
      const int atom = (2 * s + (j >> 2)) * 16 + qd * 4 + (j & 3);
      au[j] = bf16u(res[1][atom][h * 8 + (l15 & 7)]);
    }
    *(ushort8*)(vfb + (size_t)(((b * 8 + h) * 2 + s) * 64 + ln) * 8) = au;
  }
}

// ---------------------------------------------------------------------------
// Kernel 2: fully-MFMA fused attention, fragment-fed.
// K/V frags: 6 coalesced global 16B loads/wave (L2-hot), issued at entry.
// Q and O inter-wave exchange: bf16 in swizzled frag-readable layout ->
// qf / O-proj A-frags are single ds_read_b128. One 16 KB LDS buffer reused:
// x f32 (16KB) -> Q bf16 (first 8KB) + O bf16 (second 8KB) -> osb (first 8KB).
// ---------------------------------------------------------------------------
__global__ __launch_bounds__(512, 4) void attn_kernel(
    const float* __restrict__ x,
    const unsigned short* __restrict__ kfb, const unsigned short* __restrict__ vfb,
    const int* __restrict__ batch_nodes,
    const __hip_bfloat16* __restrict__ Wqb, const float* __restrict__ bq,
    const __hip_bfloat16* __restrict__ Wob, const float* __restrict__ bo,
    __hip_bfloat16* __restrict__ omid) {
  __shared__ float buf[64 * C_];     // 16 KB, multi-phase

  const int b    = blockIdx.y;
  const int m0   = blockIdx.x * 64;
  const int tid  = threadIdx.x;
  const int lane = tid & 63;
  const int w    = __builtin_amdgcn_readfirstlane(tid >> 6);   // 0..7
  const int h    = w;
  const int quad = lane >> 4;
  const int l15  = lane & 15;
  const int vq   = w & 3;            // vox block for projections
  const int cq   = w >> 2;           // co half for projections

  // ---- issue K/V fragment loads immediately (latency hides under Q-proj) --
  bf16x8 kf[4], vf[2];
  #pragma unroll
  for (int a = 0; a < 4; ++a)
    kf[a] = __builtin_bit_cast(bf16x8,
        *(const ushort8*)(kfb + (size_t)(((b * 8 + h) * 4 + a) * 64 + lane) * 8));
  #pragma unroll
  for (int s = 0; s < 2; ++s)
    vf[s] = __builtin_bit_cast(bf16x8,
        *(const ushort8*)(vfb + (size_t)(((b * 8 + h) * 2 + s) * 64 + lane) * 8));

  // ---- stage x tile [c][vox] via global_load_lds ----
  #pragma unroll
  for (int j = 0; j < 2; ++j) {
    const int cidx = w * 2 + j;
    const int c  = cidx * 4 + (lane >> 4);
    const int v4 = (lane & 15) * 4;
    const float* gsrc = x + (size_t)(b * C_ + c) * MVOX + m0 + v4;
    __builtin_amdgcn_global_load_lds((gas_u32*)gsrc,
                                     (las_u32*)&buf[cidx * 256], 16, 0, 0);
  }
  __syncthreads();

  // ---- Q projection via MFMA: D[vox][co], wave = 16 vox x 32 co ----
  f32x4 qacc[2];
  {
    bf16x8 af[2];
    #pragma unroll
    for (int kk = 0; kk < 2; ++kk) {
      ushort8 au;
      #pragma unroll
      for (int j = 0; j < 8; ++j)
        au[j] = bf16u(buf[(kk * 32 + quad * 8 + j) * 64 + vq * 16 + l15]);
      af[kk] = __builtin_bit_cast(bf16x8, au);
    }
    #pragma unroll
    for (int nf2 = 0; nf2 < 2; ++nf2) {
      const int nf = cq * 2 + nf2;
      const float bqv = bq[nf * 16 + l15] * 0.3535533905932738f;
      qacc[nf2] = {bqv, bqv, bqv, bqv};
      #pragma unroll
      for (int kk = 0; kk < 2; ++kk) {
        const bf16x8 bf = *(const bf16x8*)(Wqb + (((nf * 2 + kk) << 6) + lane) * 8);
        qacc[nf2] = __builtin_amdgcn_mfma_f32_16x16x32_bf16(af[kk], bf, qacc[nf2], 0, 0, 0);
      }
    }
  }
  __syncthreads();   // all x reads done -> buf becomes Q(bf16)/O(bf16)

  // write Q bf16 into first 8KB, swizzled: qb[vox][(h' ^ (vox&7))*8 + c&7]
  unsigned short* qb = (unsigned short*)buf;
  #pragma unroll
  for (int nf2 = 0; nf2 < 2; ++nf2) {
    const int co = (cq * 2 + nf2) * 16 + l15;
    #pragma unroll
    for (int r = 0; r < 4; ++r) {
      const int vr = vq * 16 + quad * 4 + r;
      qb[vr * 64 + (((co >> 3) ^ (vr & 7)) << 3) + (co & 7)] = bf16u(qacc[nf2][r]);
    }
  }
  __syncthreads();

  // ================== MFMA attention core ==================
  const int nv = batch_nodes[b];
  unsigned short* ob = (unsigned short*)buf + 4096;   // second 8KB

  f32x4 oacc[4];
  #pragma unroll
  for (int v = 0; v < 4; ++v)
    #pragma unroll
    for (int r = 0; r < 4; ++r) oacc[v][r] = 0.f;

  const f32x4 zero4 = {0.f, 0.f, 0.f, 0.f};
  #pragma unroll
  for (int v = 0; v < 4; ++v) {
    // Q B-frag: one b128 from swizzled qb (quad>=1 slots garbage; kf zeros)
    const int qrow = v * 16 + l15;
    const bf16x8 qf = __builtin_bit_cast(bf16x8,
        *(const ushort8*)&qb[qrow * 64 + ((h ^ (qrow & 7)) << 3)]);

    f32x4 st[4];
    #pragma unroll
    for (int a = 0; a < 4; ++a)
      st[a] = __builtin_amdgcn_mfma_f32_16x16x32_bf16(kf[a], qf, zero4, 0, 0, 0);

    // mask + row max (in-lane 16 atoms + cross-group xor 16/32)
    float m = -1e30f;
    #pragma unroll
    for (int a = 0; a < 4; ++a)
      #pragma unroll
      for (int r = 0; r < 4; ++r) {
        const int atom = a * 16 + quad * 4 + r;
        const float val = (atom < nv) ? st[a][r] : -1e30f;
        st[a][r] = val;
        m = fmaxf(m, val);
      }
    m = fmaxf(m, __shfl_xor(m, 16, 64));
    m = fmaxf(m, __shfl_xor(m, 32, 64));
    float ssum = 0.f;
    #pragma unroll
    for (int a = 0; a < 4; ++a)
      #pragma unroll
      for (int r = 0; r < 4; ++r) {
        const float p = __expf(st[a][r] - m);
        st[a][r] = p;
        ssum += p;
      }
    ssum += __shfl_xor(ssum, 16, 64);
    ssum += __shfl_xor(ssum, 32, 64);
    const float inv = 1.f / ssum;

    #pragma unroll
    for (int s = 0; s < 2; ++s) {
      ushort8 pu;
      #pragma unroll
      for (int j = 0; j < 8; ++j)
        pu[j] = bf16u(st[2 * s + (j >> 2)][j & 3] * inv);
      const bf16x8 pa = __builtin_bit_cast(bf16x8, pu);
      oacc[v] = __builtin_amdgcn_mfma_f32_16x16x32_bf16(pa, vf[s], oacc[v], 0, 0, 0);
    }
  }

  // write O bf16 into second 8KB, swizzled (c = h*8+l15, valid l15<8)
  if (l15 < 8) {
    const int c = h * 8 + l15;
    #pragma unroll
    for (int v = 0; v < 4; ++v)
      #pragma unroll
      for (int r = 0; r < 4; ++r) {
        const int vxr = v * 16 + quad * 4 + r;
        ob[vxr * 64 + ((h ^ (vxr & 7)) << 3) + l15] = bf16u(oacc[v][r]);
      }
  }
  __syncthreads();   // all O written, all qb reads done

  // ---- O projection via MFMA + ReLU -> osb (first 8KB) ----
  {
    bf16x8 af[2];
    #pragma unroll
    for (int kk = 0; kk < 2; ++kk) {
      const int row = vq * 16 + l15;
      af[kk] = __builtin_bit_cast(bf16x8,
          *(const ushort8*)&ob[row * 64 + (((kk * 4 + quad) ^ (row & 7)) << 3)]);
    }
    f32x4 oac[2];
    #pragma unroll
    for (int nf2 = 0; nf2 < 2; ++nf2) {
      const int nf = cq * 2 + nf2;
      const float bov = bo[nf * 16 + l15];
      oac[nf2] = {bov, bov, bov, bov};
      #pragma unroll
      for (int kk = 0; kk < 2; ++kk) {
        const bf16x8 bf = *(const bf16x8*)(Wob + (((nf * 2 + kk) << 6) + lane) * 8);
        oac[nf2] = __builtin_amdgcn_mfma_f32_16x16x32_bf16(af[kk], bf, oac[nf2], 0, 0, 0);
      }
    }
    __syncthreads();   // all ob reads done; osb overwrites qb region
    unsigned short* osb = (unsigned short*)buf;
    #pragma unroll
    for (int nf2 = 0; nf2 < 2; ++nf2) {
      const int co = (cq * 2 + nf2) * 16 + l15;
      #pragma unroll
      for (int r = 0; r < 4; ++r) {
        const int vr = vq * 16 + quad * 4 + r;
        osb[vr * 64 + (((co >> 3) ^ (vr & 7)) << 3) + (co & 7)] =
            bf16u(fmaxf(oac[nf2][r], 0.f));
      }
    }
  }
  __syncthreads();

  // ---- coalesced store: osb holds conv's swizzled channel-last layout ----
  *(ushort8*)(omid + (size_t)(b * MVOX + m0) * C_ + tid * 8) =
      *(const ushort8*)&((unsigned short*)buf)[tid * 8];
}

// ---------------------------------------------------------------------------
// Kernel 3: conv3d 3x3x3 circular (unchanged; near its ~23 us memory floor).
// ---------------------------------------------------------------------------
#define LOADB(dst, DX, DY, DZ)                                              \
  {                                                                         \
    const int zp_ = ((lane & 31) + (DZ) + 31) & 31;                         \
    const int sw_ = zp_ & 7;                                                \
    _Pragma("unroll")                                                       \
    for (int ks_ = 0; ks_ < 4; ++ks_) {                                     \
      const int phys_ = (ks_ * 2 + (lane >> 5)) ^ sw_;                      \
      _Pragma("unroll")                                                     \
      for (int i_ = 0; i_ < 2; ++i_) {                                      \
        const int hl_ = (lp + (DX)) * 4 + (i_ + (DY));                      \
        (dst)[i_ * 4 + ks_] =                                               \
            *(const bf16x8*)&halo[((hl_ * 32 + zp_) * 8 + phys_) * 8];      \
      }                                                                     \
    }                                                                       \
  }

#define LOADW(T2)                                                           \
  _Pragma("unroll")                                                         \
  for (int ks_ = 0; ks_ < 4; ++ks_)                                         \
    wf[(T2) % 3][ks_] =                                                     \
        *(const bf16x8*)(Wt4 + ((((T2) * 2 + coh) * 4 + ks_) << 9) + lane * 8);

#define DOMFMA(src, T)                                                      \
  _Pragma("unroll")                                                         \
  for (int ks_ = 0; ks_ < 4; ++ks_)                                         \
    _Pragma("unroll")                                                       \
    for (int i_ = 0; i_ < 2; ++i_)                                          \
      acc[i_] = __builtin_amdgcn_mfma_f32_32x32x16_bf16(                    \
          wf[(T) % 3][ks_], (src)[i_ * 4 + ks_], acc[i_], 0, 0, 0);

__global__ __launch_bounds__(256, 2) void conv_kernel(
    const __hip_bfloat16* __restrict__ omid,
    const __hip_bfloat16* __restrict__ Wt4,
    const float* __restrict__ bc,
    const float* __restrict__ xin,
    float* __restrict__ out) {
  __shared__ __hip_bfloat16 halo[512 * 64];   // 64 KB

  const int b    = blockIdx.y;
  const int x0   = (blockIdx.x >> 4) * 2;
  const int y0   = (blockIdx.x & 15) * 2;
  const int tid  = threadIdx.x;
  const int lane = tid & 63;
  const int w    = tid >> 6;
  const int coh  = w & 1;
  const int lp   = w >> 1;

  {
    const __hip_bfloat16* src = omid + (size_t)b * MVOX * C_;
    #pragma unroll
    for (int n = 0; n < 16; ++n) {
      const int chunk = w * 16 + n;
      const int li = chunk >> 2;
      const int zb = (chunk & 3) * 8;
      const int gx = (x0 - 1 + (li >> 2)) & 31;
      const int gy = (y0 - 1 + (li & 3)) & 31;
      const __hip_bfloat16* gsrc = src + (size_t)(gx * 1024 + gy * 32 + zb) * C_ + lane * 8;
      __builtin_amdgcn_global_load_lds((gas_u32*)gsrc,
                                       (las_u32*)&halo[chunk * 512], 16, 0, 0);
    }
  }

  bf16x8 wf[3][4];
  LOADW(0);
  LOADW(1);
  __syncthreads();

  f32x16 acc[2];
  #pragma unroll
  for (int i = 0; i < 2; ++i)
    #pragma unroll
    for (int r = 0; r < 16; ++r) acc[i][r] = 0.f;

  bf16x8 bA[8], bB[8];
  LOADB(bA, 0, 0, 0);

  #pragma unroll
  for (int t = 0; t < 27; ++t) {
    const int dxn = (t + 1) / 9, dyn = ((t + 1) / 3) % 3, dzn = (t + 1) % 3;
    if ((t & 1) == 0) {
      if (t < 26) LOADB(bB, dxn, dyn, dzn);
      if (t < 25) LOADW(t + 2);
      DOMFMA(bA, t);
    } else {
      if (t < 26) LOADB(bA, dxn, dyn, dzn);
      if (t < 25) LOADW(t + 2);
      DOMFMA(bB, t);
    }
  }

  const int z = lane & 31;
  #pragma unroll
  for (int i = 0; i < 2; ++i) {
    const int gx = x0 + lp, gy = y0 + i;
    #pragma unroll
    for (int r = 0; r < 16; ++r) {
      const int co = coh * 32 + (r & 3) + 8 * (r >> 2) + 4 * (lane >> 5);
      const size_t idx = ((size_t)(b * C_ + co)) * MVOX + gx * 1024 + gy * 32 + z;
      out[idx] = fmaxf(acc[i][r] + bc[co], 0.f) + xin[idx];
    }
  }
}

// ---------------------------------------------------------------------------
extern "C" void kernel_launch(void* const* d_in, const int* in_sizes, int n_in,
                              void* d_out, int out_size, void* d_ws, size_t ws_size,
                              hipStream_t stream) {
  const float* x   = (const float*)d_in[0];
  const float* mol = (const float*)d_in[1];
  const int*   bn  = (const int*)  d_in[2];
  const float* Wq  = (const float*)d_in[3];
  const float* bq  = (const float*)d_in[4];
  const float* Wk  = (const float*)d_in[5];
  const float* bk  = (const float*)d_in[6];
  const float* Wv  = (const float*)d_in[7];
  const float* bv  = (const float*)d_in[8];
  const float* Wo  = (const float*)d_in[9];
  const float* bo  = (const float*)d_in[10];
  const float* Wc  = (const float*)d_in[11];
  const float* bc  = (const float*)d_in[12];
  float* out = (float*)d_out;

  char* ws = (char*)d_ws;
  __hip_bfloat16* omid = (__hip_bfloat16*)ws;                     // 16,777,216 B
  __hip_bfloat16* Wt4  = (__hip_bfloat16*)(ws + 16777216);        // 221,184 B
  __hip_bfloat16* Wqb  = (__hip_bfloat16*)(ws + 16998400);        // 8,192 B
  __hip_bfloat16* Wob  = (__hip_bfloat16*)(ws + 17006592);        // 8,192 B
  __hip_bfloat16* Wkb  = (__hip_bfloat16*)(ws + 17014784);        // 16,384 B
  __hip_bfloat16* Wvb  = (__hip_bfloat16*)(ws + 17031168);        // 16,384 B
  unsigned short* kfb  = (unsigned short*)(ws + 17047552);        // 131,072 B
  unsigned short* vfb  = (unsigned short*)(ws + 17178624);        // 65,536 B

  wprep_kernel<<<dim3(528), 256, 0, stream>>>(Wc, Wq, Wo, Wk, Wv,
                                              Wt4, Wqb, Wob, Wkb, Wvb);
  kv_kernel<<<dim3(B_), 256, 0, stream>>>(mol, Wkb, bk, Wvb, bv, kfb, vfb);
  attn_kernel<<<dim3(MVOX / 64, B_), 512, 0, stream>>>(x, kfb, vfb, bn, Wqb, bq, Wob, bo, omid);
  conv_kernel<<<dim3(256, B_), 256, 0, stream>>>(omid, Wt4, bc, x, out);
}